// Round 5
// baseline (369.708 us; speedup 1.0000x reference)
//
#include <hip/hip_runtime.h>
#include <math.h>

#define B 64
#define SDIM 2048
#define FEAT 128
#define P 4
#define PK 8196
#define NCLS 7
#define PER 1000
#define NDATA 100000
#define EPSC 1e-7f
#define M_PN 0.08192f   /* (PK-P)/NDATA = 8192/100000 */
#define JCHUNKS 50
#define CS (PER / JCHUNKS)   /* 20 rows per block */
#define TILE 16              /* rows per wave-private LDS tile */
#define WCHUNK 128           /* rows per wave */
#define TCHUNK 512           /* rows per block (4 waves) */
#define NTILES (WCHUNK / TILE)  /* 8 */

// ---------------- K1: f = l2norm(f @ W + b) for both s and t ----------------
__global__ void gemm_norm_kernel(const float* __restrict__ f_s,
                                 const float* __restrict__ f_t,
                                 const float* __restrict__ W_s,
                                 const float* __restrict__ b_s,
                                 const float* __restrict__ W_t,
                                 const float* __restrict__ b_t,
                                 float* __restrict__ out_fs,
                                 float* __restrict__ out_ft)
{
    const int row = blockIdx.x;
    const int z   = blockIdx.y;
    const float* f    = z == 0 ? f_s : f_t;
    const float* W    = z == 0 ? W_s : W_t;
    const float* bias = z == 0 ? b_s : b_t;
    float* out        = z == 0 ? out_fs : out_ft;

    __shared__ __align__(16) float frow[SDIM];
    const int t  = threadIdx.x;        // 0..255
    const int d  = t & 127;
    const int kh = t >> 7;             // 0/1
    for (int k = t; k < SDIM; k += 256) frow[k] = f[row * SDIM + k];
    __syncthreads();

    float acc = 0.0f;
    const int k0 = kh * (SDIM / 2);
    for (int k = k0; k < k0 + SDIM / 2; ++k)
        acc = fmaf(frow[k], W[k * FEAT + d], acc);

    __shared__ float part[2][128];
    part[kh][d] = acc;
    __syncthreads();

    const float a = part[0][d] + part[1][d] + bias[d];

    __shared__ float red[256];
    red[t] = (t < 128) ? a * a : 0.0f;
    __syncthreads();
    for (int s = 128; s > 0; s >>= 1) {
        if (t < s) red[t] += red[t + s];
        __syncthreads();
    }
    if (t < 128) out[row * FEAT + t] = a * (1.0f / sqrtf(red[0]));
}

// ---- K2: out[z][b][k] = exp(dot(mem[ci], f[b]) / T), plus total sum S[z] ----
// 4 waves/block, wave-private 16-row LDS tiles (no barriers in main loop),
// double-buffered: load tile t+1 into regs while computing tile t from LDS.
__global__ __launch_bounds__(256)
void dots_kernel(const float* __restrict__ fsn,
                 const float* __restrict__ ftn,
                 const int*   __restrict__ contrast_idx,
                 const float* __restrict__ mem_s,
                 const float* __restrict__ mem_t,
                 float* __restrict__ out_raw,   // [2][B*PK]
                 float* __restrict__ Ssum)      // [2]
{
    const int z    = blockIdx.z;
    const int b    = blockIdx.y;
    const int t256 = threadIdx.x;
    const int wave = t256 >> 6;        // 0..3
    const int l    = t256 & 63;
    const int kchunk = blockIdx.x * TCHUNK;
    const int kwave  = kchunk + wave * WCHUNK;

    const float* f   = (z == 0 ? fsn : ftn) + b * FEAT;
    const float* mem = (z == 0 ? mem_t : mem_s);   // NOTE the cross pairing

    __shared__ __align__(16) float4 rows[4][TILE * 32];  // 4 x 8 KB, swizzled
    __shared__ __align__(16) float  fl[FEAT];            // 512 B
    __shared__ int cis[TCHUNK];                          // 2 KB

    // block-cooperative stage of f and the ci chunk (only block-wide barrier)
    if (t256 < FEAT) fl[t256] = f[t256];
    for (int i = t256; i < TCHUNK; i += 256) {
        const int k = kchunk + i;
        cis[i] = contrast_idx[(size_t)b * PK + (k < PK ? k : PK - 1)];
    }
    __syncthreads();

    float4* myrows = rows[wave];
    const int cbase = wave * WCHUNK;

    const int g32 = l & 31;            // float4 slot (stage)
    const int rh  = l >> 5;            // 0/1: row-of-pair (stage)
    const int r_c = l & 15;            // row this lane computes
    const int q   = l >> 4;            // quarter 0..3 (compute)
    const int xk  = r_c & 7;           // swizzle key
    const float inv_t = 1.0f / 0.07f;
    const size_t obase = (size_t)z * (B * PK) + (size_t)b * PK;
    const float4* fp4 = (const float4*)fl;

    float lsum = 0.0f;
    float4 reg[8];

    // prologue: load tile 0 into regs (indices are clamped, always valid)
    #pragma unroll
    for (int p = 0; p < 8; ++p) {
        const int r  = 2 * p + rh;
        const int ci = cis[cbase + r];
        reg[p] = *(const float4*)(mem + (size_t)ci * FEAT + g32 * 4);
    }

    for (int t = 0; t < NTILES; ++t) {
        // write current tile regs -> wave-private LDS (swizzled)
        #pragma unroll
        for (int p = 0; p < 8; ++p) {
            const int r = 2 * p + rh;
            myrows[r * 32 + (g32 ^ (r & 7))] = reg[p];
        }
        // issue next tile's global loads (latency hidden under compute)
        if (t + 1 < NTILES) {
            #pragma unroll
            for (int p = 0; p < 8; ++p) {
                const int r  = 2 * p + rh;
                const int ci = cis[cbase + (t + 1) * TILE + r];
                reg[p] = *(const float4*)(mem + (size_t)ci * FEAT + g32 * 4);
            }
        }
        // compute tile t: lane = quarter q of row r_c
        float dot = 0.0f;
        #pragma unroll
        for (int i = 0; i < 8; ++i) {
            const int g = q * 8 + i;
            const float4 m  = myrows[r_c * 32 + (g ^ xk)];
            const float4 ff = fp4[g];
            dot = fmaf(m.x, ff.x, dot);
            dot = fmaf(m.y, ff.y, dot);
            dot = fmaf(m.z, ff.z, dot);
            dot = fmaf(m.w, ff.w, dot);
        }
        // combine the 4 quarters (lanes r_c, r_c+16, r_c+32, r_c+48)
        dot += __shfl_xor(dot, 16);
        dot += __shfl_xor(dot, 32);

        const int krow = kwave + t * TILE + r_c;
        if (q == 0 && krow < PK) {
            const float val = expf(dot * inv_t);
            out_raw[obase + krow] = val;
            lsum += val;
        }
    }

    // reduce lsum over lanes 0..15 (others hold 0), one atomic per wave
    lsum += __shfl_xor(lsum, 8);
    lsum += __shfl_xor(lsum, 4);
    lsum += __shfl_xor(lsum, 2);
    lsum += __shfl_xor(lsum, 1);
    if (l == 0) atomicAdd(&Ssum[z], lsum);
}

// ---- K3: accumulate acc[z] = sum logD1 + P * sum logD0 (weighted) ----
__global__ void ccd_loss_kernel(const float* __restrict__ out_raw,
                                const float* __restrict__ Ssum,
                                float* __restrict__ acc)   // [2]
{
    const int z = blockIdx.y;
    const float S = Ssum[z];
    // normalized v = out * c ; c = B*PK / (S * NDATA)
    const float c = ((float)(B * PK)) / (S * (float)NDATA);

    const int total = B * PK;
    float contrib = 0.0f;
    for (int i = blockIdx.x * blockDim.x + threadIdx.x; i < total;
         i += gridDim.x * blockDim.x) {
        const float v = out_raw[(size_t)z * total + i] * c;
        const int k = i % PK;
        if (k < P) {
            contrib += logf(v / (v + M_PN + EPSC));
        } else {
            contrib += (float)P * logf(M_PN / (v + M_PN + EPSC));
        }
    }
    __shared__ float red[256];
    red[threadIdx.x] = contrib;
    __syncthreads();
    for (int s = 128; s > 0; s >>= 1) {
        if (threadIdx.x < s) red[threadIdx.x] += red[threadIdx.x + s];
        __syncthreads();
    }
    if (threadIdx.x == 0) atomicAdd(&acc[z], red[0]);
}

// ---- K4: upd[z][b] = l2norm(mem[idx[b]]*0.5 + f[b]*0.5) ----
__global__ void upd_kernel(const float* __restrict__ fsn,
                           const float* __restrict__ ftn,
                           const int*   __restrict__ idx,
                           const float* __restrict__ mem_s,
                           const float* __restrict__ mem_t,
                           float* __restrict__ upd)   // [2][B*FEAT]
{
    const int z = blockIdx.y;
    const int b = blockIdx.x;
    const int d = threadIdx.x;  // 128
    const float* mem = z == 0 ? mem_s : mem_t;
    const float* f   = z == 0 ? fsn : ftn;
    const int i = idx[b];
    const float v = mem[(size_t)i * FEAT + d] * 0.5f + f[b * FEAT + d] * 0.5f;
    __shared__ float red[128];
    red[d] = v * v;
    __syncthreads();
    for (int s = 64; s > 0; s >>= 1) {
        if (d < s) red[d] += red[d + s];
        __syncthreads();
    }
    upd[(size_t)z * (B * FEAT) + b * FEAT + d] = v * (1.0f / sqrtf(red[0]));
}

// ---- K4b: remap[e] = last b with idx[b]==class_index[e], else -1 ----
__global__ void remap_kernel(const int* __restrict__ class_index,
                             const int* __restrict__ idx,
                             int* __restrict__ remap)
{
    const int e = blockIdx.x * 256 + threadIdx.x;
    if (e >= NCLS * PER) return;
    const int ci = class_index[e];
    int rb = -1;
    for (int b = B - 1; b >= 0; --b) {
        if (idx[b] == ci) { rb = b; break; }   // last occurrence wins
    }
    remap[e] = rb;
}

// ---- K5a: partial[z][c][d] += sum_{j in chunk} relu(new_mem[ci[c,j]][d]) ----
__global__ void anchors_partial_kernel(const int* __restrict__ class_index,
                                       const int* __restrict__ remap,
                                       const float* __restrict__ mem_s,
                                       const float* __restrict__ mem_t,
                                       const float* __restrict__ upd,
                                       float* __restrict__ partial) // [2][NCLS*FEAT]
{
    const int z     = blockIdx.z;
    const int c     = blockIdx.y;
    const int chunk = blockIdx.x;
    const int d     = threadIdx.x;  // 128
    const float* mem = z == 0 ? mem_s : mem_t;
    const float* u   = upd + (size_t)z * (B * FEAT);
    float acc = 0.0f;
    #pragma unroll 4
    for (int j = chunk * CS; j < chunk * CS + CS; ++j) {
        const int e = c * PER + j;
        const int ci = class_index[e];
        const int rb = remap[e];
        const float* row = (rb >= 0) ? (u + rb * FEAT) : (mem + (size_t)ci * FEAT);
        const float v = row[d];
        acc += v > 0.0f ? v : 0.0f;
    }
    atomicAdd(&partial[(size_t)z * (NCLS * FEAT) + c * FEAT + d], acc);
}

// ---- K5b: anchors[z][c] = l2norm(partial / PER) ----
__global__ void anchors_finish_kernel(const float* __restrict__ partial,
                                      float* __restrict__ anchors)  // [2][NCLS*FEAT]
{
    const int z = blockIdx.y;
    const int c = blockIdx.x;
    const int d = threadIdx.x;  // 128
    const float meanv = partial[(size_t)z * (NCLS * FEAT) + c * FEAT + d]
                        * (1.0f / (float)PER);
    __shared__ float red[128];
    red[d] = meanv * meanv;
    __syncthreads();
    for (int s = 64; s > 0; s >>= 1) {
        if (d < s) red[d] += red[d + s];
        __syncthreads();
    }
    anchors[(size_t)z * (NCLS * FEAT) + c * FEAT + d] = meanv * (1.0f / sqrtf(red[0]));
}

// ---- K6: relation loss (softmax KL) + final CCD assembly ----
__global__ void final_kernel(const float* __restrict__ fsn,
                             const float* __restrict__ ftn,
                             const float* __restrict__ anchors,
                             const float* __restrict__ acc,
                             float* __restrict__ d_out)
{
    __shared__ float sa[NCLS * FEAT];
    __shared__ float ta[NCLS * FEAT];
    const int tid = threadIdx.x;  // 64 threads
    for (int i = tid; i < NCLS * FEAT; i += 64) {
        sa[i] = anchors[i];
        ta[i] = anchors[NCLS * FEAT + i];
    }
    __syncthreads();

    const int b = tid;
    float srel[NCLS], trel[NCLS];
    for (int j = 0; j < NCLS; ++j) { srel[j] = 0.0f; trel[j] = 0.0f; }
    for (int d = 0; d < FEAT; ++d) {
        const float fs = fsn[b * FEAT + d];
        const float ft = ftn[b * FEAT + d];
        #pragma unroll
        for (int j = 0; j < NCLS; ++j) {
            srel[j] = fmaf(fs, sa[j * FEAT + d], srel[j]);
            trel[j] = fmaf(ft, ta[j * FEAT + d], trel[j]);
        }
    }
    const float inv_t = 1.0f / 0.07f;
    float smax = -1e30f, tmax = -1e30f;
    for (int j = 0; j < NCLS; ++j) {
        srel[j] *= inv_t; trel[j] *= inv_t;
        smax = fmaxf(smax, srel[j]);
        tmax = fmaxf(tmax, trel[j]);
    }
    float ssum = 0.0f, tsum = 0.0f;
    float texp[NCLS];
    for (int j = 0; j < NCLS; ++j) {
        ssum += expf(srel[j] - smax);
        texp[j] = expf(trel[j] - tmax);
        tsum += texp[j];
    }
    const float lse_s = logf(ssum);
    float contrib = 0.0f;
    for (int j = 0; j < NCLS; ++j) {
        const float tgt = texp[j] / tsum;
        const float log_in = srel[j] - smax - lse_s;   // log_softmax
        contrib += tgt * (logf(tgt + 1e-30f) - log_in);
    }
    for (int off = 32; off > 0; off >>= 1) contrib += __shfl_down(contrib, off);
    if (tid == 0) {
        d_out[1] = contrib / (float)B;
        d_out[0] = -(acc[0] + acc[1]) / (float)(B * P);
    }
}

extern "C" void kernel_launch(void* const* d_in, const int* in_sizes, int n_in,
                              void* d_out_v, int out_size, void* d_ws, size_t ws_size,
                              hipStream_t stream)
{
    const float* f_s = (const float*)d_in[0];
    const float* f_t = (const float*)d_in[1];
    const int*   idx = (const int*)d_in[2];
    /* d_in[3] batch_label: unused by reference */
    const int*   class_index = (const int*)d_in[4];
    /* d_in[5] num_pos == 4 (hardcoded) */
    const int*   contrast_idx = (const int*)d_in[6];
    const float* W_s = (const float*)d_in[7];
    const float* b_s = (const float*)d_in[8];
    const float* W_t = (const float*)d_in[9];
    const float* b_t = (const float*)d_in[10];
    const float* mem_s = (const float*)d_in[11];
    const float* mem_t = (const float*)d_in[12];

    float* out    = (float*)d_out_v;
    float* out_fs = out + 2;               // f_s output (64*128)
    float* out_ft = out + 2 + B * FEAT;    // f_t output

    // workspace layout (floats)
    float* ws      = (float*)d_ws;
    float* out_raw = ws;                          // 2 * B*PK   = 1,049,088
    float* Ssum    = out_raw + 2 * (B * PK);      // 2
    float* acc     = Ssum + 2;                    // 2
    float* upd     = acc + 2;                     // 2 * B*FEAT = 16,384
    float* anchors = upd + 2 * (B * FEAT);        // 2 * NCLS*FEAT = 1,792
    float* partial = anchors + 2 * (NCLS * FEAT); // 2 * NCLS*FEAT = 1,792
    int*   remap   = (int*)(partial + 2 * (NCLS * FEAT));  // 7,000 ints

    // zero Ssum[2] + acc[2] + partial[1792]
    hipMemsetAsync(Ssum, 0, 4 * sizeof(float), stream);
    hipMemsetAsync(partial, 0, 2 * NCLS * FEAT * sizeof(float), stream);

    dim3 g1(B, 2);
    gemm_norm_kernel<<<g1, 256, 0, stream>>>(f_s, f_t, W_s, b_s, W_t, b_t,
                                             out_fs, out_ft);
    dim3 g2((PK + TCHUNK - 1) / TCHUNK, B, 2);   // 17 x 64 x 2
    dots_kernel<<<g2, 256, 0, stream>>>(out_fs, out_ft, contrast_idx,
                                        mem_s, mem_t, out_raw, Ssum);
    dim3 g3(256, 2);
    ccd_loss_kernel<<<g3, 256, 0, stream>>>(out_raw, Ssum, acc);
    dim3 g4(B, 2);
    upd_kernel<<<g4, 128, 0, stream>>>(out_fs, out_ft, idx, mem_s, mem_t, upd);
    remap_kernel<<<(NCLS * PER + 255) / 256, 256, 0, stream>>>(class_index, idx, remap);
    dim3 g5a(JCHUNKS, NCLS, 2);
    anchors_partial_kernel<<<g5a, 128, 0, stream>>>(class_index, remap,
                                                    mem_s, mem_t, upd, partial);
    dim3 g5b(NCLS, 2);
    anchors_finish_kernel<<<g5b, 128, 0, stream>>>(partial, anchors);
    final_kernel<<<1, 64, 0, stream>>>(out_fs, out_ft, anchors, acc, out);
}

// Round 6
// 215.931 us; speedup vs baseline: 1.7122x; 1.7122x over previous
//
#include <hip/hip_runtime.h>
#include <math.h>

#define B 64
#define SDIM 2048
#define FEAT 128
#define P 4
#define PK 8196
#define NCLS 7
#define PER 1000
#define NDATA 100000
#define EPSC 1e-7f
#define M_PN 0.08192f   /* (PK-P)/NDATA = 8192/100000 */
#define JCHUNKS 50
#define CS (PER / JCHUNKS)   /* 20 rows per block */
#define TILE 16              /* rows per wave-private LDS tile */
#define WCHUNK 128           /* rows per wave */
#define TCHUNK 512           /* rows per block (4 waves) */
#define NTILES (WCHUNK / TILE)  /* 8 */

// ---------------- K1: f = l2norm(f @ W + b) for both s and t ----------------
__global__ void gemm_norm_kernel(const float* __restrict__ f_s,
                                 const float* __restrict__ f_t,
                                 const float* __restrict__ W_s,
                                 const float* __restrict__ b_s,
                                 const float* __restrict__ W_t,
                                 const float* __restrict__ b_t,
                                 float* __restrict__ out_fs,
                                 float* __restrict__ out_ft)
{
    const int row = blockIdx.x;
    const int z   = blockIdx.y;
    const float* f    = z == 0 ? f_s : f_t;
    const float* W    = z == 0 ? W_s : W_t;
    const float* bias = z == 0 ? b_s : b_t;
    float* out        = z == 0 ? out_fs : out_ft;

    __shared__ __align__(16) float frow[SDIM];
    const int t  = threadIdx.x;        // 0..255
    const int d  = t & 127;
    const int kh = t >> 7;             // 0/1
    for (int k = t; k < SDIM; k += 256) frow[k] = f[row * SDIM + k];
    __syncthreads();

    float acc = 0.0f;
    const int k0 = kh * (SDIM / 2);
    for (int k = k0; k < k0 + SDIM / 2; ++k)
        acc = fmaf(frow[k], W[k * FEAT + d], acc);

    __shared__ float part[2][128];
    part[kh][d] = acc;
    __syncthreads();

    const float a = part[0][d] + part[1][d] + bias[d];

    __shared__ float red[256];
    red[t] = (t < 128) ? a * a : 0.0f;
    __syncthreads();
    for (int s = 128; s > 0; s >>= 1) {
        if (t < s) red[t] += red[t + s];
        __syncthreads();
    }
    if (t < 128) out[row * FEAT + t] = a * (1.0f / sqrtf(red[0]));
}

// ---- K2: out[z][b][k] = exp(dot(mem[ci], f[b]) / T), plus total sum S[z] ----
// 4 waves/block, wave-private 16-row LDS tiles (no barriers in main loop).
// Double-buffer through EIGHT NAMED float4 registers (rule #20: an array here
// goes to scratch -> 500+ MB of spill traffic, measured R5).
__global__ __launch_bounds__(256)
void dots_kernel(const float* __restrict__ fsn,
                 const float* __restrict__ ftn,
                 const int*   __restrict__ contrast_idx,
                 const float* __restrict__ mem_s,
                 const float* __restrict__ mem_t,
                 float* __restrict__ out_raw,   // [2][B*PK]
                 float* __restrict__ Ssum)      // [2]
{
    const int z    = blockIdx.z;
    const int b    = blockIdx.y;
    const int t256 = threadIdx.x;
    const int wave = t256 >> 6;        // 0..3
    const int l    = t256 & 63;
    const int kchunk = blockIdx.x * TCHUNK;
    const int kwave  = kchunk + wave * WCHUNK;

    const float* f   = (z == 0 ? fsn : ftn) + b * FEAT;
    const float* mem = (z == 0 ? mem_t : mem_s);   // NOTE the cross pairing

    __shared__ __align__(16) float4 rows[4][TILE * 32];  // 4 x 8 KB, swizzled
    __shared__ __align__(16) float  fl[FEAT];            // 512 B
    __shared__ int cis[TCHUNK];                          // 2 KB

    // block-cooperative stage of f and the ci chunk (only block-wide barrier)
    if (t256 < FEAT) fl[t256] = f[t256];
    for (int i = t256; i < TCHUNK; i += 256) {
        const int k = kchunk + i;
        cis[i] = contrast_idx[(size_t)b * PK + (k < PK ? k : PK - 1)];
    }
    __syncthreads();

    float4* myrows = rows[wave];
    const int cbase = wave * WCHUNK;

    const int g32 = l & 31;            // float4 slot (stage)
    const int rh  = l >> 5;            // 0/1: row-of-pair (stage)
    const int r_c = l & 15;            // row this lane computes
    const int q   = l >> 4;            // quarter 0..3 (compute)
    const int xk  = r_c & 7;           // swizzle key
    const float inv_t = 1.0f / 0.07f;
    const size_t obase = (size_t)z * (B * PK) + (size_t)b * PK;
    const float4* fp4 = (const float4*)fl;
    const float* memg = mem + g32 * 4;

    float lsum = 0.0f;

    // eight NAMED prefetch registers (never an array)
    float4 r0, r1, r2, r3, r4, r5, r6, r7;

#define LOADR(p, tt) \
    (*(const float4*)(memg + (size_t)cis[cbase + (tt) * TILE + 2 * (p) + rh] * FEAT))
#define WRITER(p, rv) \
    do { const int rr_ = 2 * (p) + rh; \
         myrows[rr_ * 32 + (g32 ^ (rr_ & 7))] = (rv); } while (0)

    // prologue: load tile 0 (indices are clamped, always valid)
    r0 = LOADR(0, 0); r1 = LOADR(1, 0); r2 = LOADR(2, 0); r3 = LOADR(3, 0);
    r4 = LOADR(4, 0); r5 = LOADR(5, 0); r6 = LOADR(6, 0); r7 = LOADR(7, 0);

    for (int t = 0; t < NTILES; ++t) {
        // write current tile regs -> wave-private LDS (swizzled)
        WRITER(0, r0); WRITER(1, r1); WRITER(2, r2); WRITER(3, r3);
        WRITER(4, r4); WRITER(5, r5); WRITER(6, r6); WRITER(7, r7);

        // issue next tile's global loads (latency hidden under compute)
        if (t + 1 < NTILES) {
            const int tn = t + 1;
            r0 = LOADR(0, tn); r1 = LOADR(1, tn);
            r2 = LOADR(2, tn); r3 = LOADR(3, tn);
            r4 = LOADR(4, tn); r5 = LOADR(5, tn);
            r6 = LOADR(6, tn); r7 = LOADR(7, tn);
        }

        // compute tile t: lane = quarter q of row r_c
        float dot = 0.0f;
        #pragma unroll
        for (int i = 0; i < 8; ++i) {
            const int g = q * 8 + i;
            const float4 m  = myrows[r_c * 32 + (g ^ xk)];
            const float4 ff = fp4[g];
            dot = fmaf(m.x, ff.x, dot);
            dot = fmaf(m.y, ff.y, dot);
            dot = fmaf(m.z, ff.z, dot);
            dot = fmaf(m.w, ff.w, dot);
        }
        // combine the 4 quarters (lanes r_c, r_c+16, r_c+32, r_c+48)
        dot += __shfl_xor(dot, 16);
        dot += __shfl_xor(dot, 32);

        const int krow = kwave + t * TILE + r_c;
        if (q == 0 && krow < PK) {
            const float val = expf(dot * inv_t);
            out_raw[obase + krow] = val;
            lsum += val;
        }
    }
#undef LOADR
#undef WRITER

    // reduce lsum over lanes 0..15 (others hold 0), one atomic per wave
    lsum += __shfl_xor(lsum, 8);
    lsum += __shfl_xor(lsum, 4);
    lsum += __shfl_xor(lsum, 2);
    lsum += __shfl_xor(lsum, 1);
    if (l == 0) atomicAdd(&Ssum[z], lsum);
}

// ---- K3: accumulate acc[z] = sum logD1 + P * sum logD0 (weighted) ----
__global__ void ccd_loss_kernel(const float* __restrict__ out_raw,
                                const float* __restrict__ Ssum,
                                float* __restrict__ acc)   // [2]
{
    const int z = blockIdx.y;
    const float S = Ssum[z];
    // normalized v = out * c ; c = B*PK / (S * NDATA)
    const float c = ((float)(B * PK)) / (S * (float)NDATA);

    const int total = B * PK;
    float contrib = 0.0f;
    for (int i = blockIdx.x * blockDim.x + threadIdx.x; i < total;
         i += gridDim.x * blockDim.x) {
        const float v = out_raw[(size_t)z * total + i] * c;
        const int k = i % PK;
        if (k < P) {
            contrib += logf(v / (v + M_PN + EPSC));
        } else {
            contrib += (float)P * logf(M_PN / (v + M_PN + EPSC));
        }
    }
    __shared__ float red[256];
    red[threadIdx.x] = contrib;
    __syncthreads();
    for (int s = 128; s > 0; s >>= 1) {
        if (threadIdx.x < s) red[threadIdx.x] += red[threadIdx.x + s];
        __syncthreads();
    }
    if (threadIdx.x == 0) atomicAdd(&acc[z], red[0]);
}

// ---- K4: upd[z][b] = l2norm(mem[idx[b]]*0.5 + f[b]*0.5) ----
__global__ void upd_kernel(const float* __restrict__ fsn,
                           const float* __restrict__ ftn,
                           const int*   __restrict__ idx,
                           const float* __restrict__ mem_s,
                           const float* __restrict__ mem_t,
                           float* __restrict__ upd)   // [2][B*FEAT]
{
    const int z = blockIdx.y;
    const int b = blockIdx.x;
    const int d = threadIdx.x;  // 128
    const float* mem = z == 0 ? mem_s : mem_t;
    const float* f   = z == 0 ? fsn : ftn;
    const int i = idx[b];
    const float v = mem[(size_t)i * FEAT + d] * 0.5f + f[b * FEAT + d] * 0.5f;
    __shared__ float red[128];
    red[d] = v * v;
    __syncthreads();
    for (int s = 64; s > 0; s >>= 1) {
        if (d < s) red[d] += red[d + s];
        __syncthreads();
    }
    upd[(size_t)z * (B * FEAT) + b * FEAT + d] = v * (1.0f / sqrtf(red[0]));
}

// ---- K4b: remap[e] = last b with idx[b]==class_index[e], else -1 ----
__global__ void remap_kernel(const int* __restrict__ class_index,
                             const int* __restrict__ idx,
                             int* __restrict__ remap)
{
    const int e = blockIdx.x * 256 + threadIdx.x;
    if (e >= NCLS * PER) return;
    const int ci = class_index[e];
    int rb = -1;
    for (int b = B - 1; b >= 0; --b) {
        if (idx[b] == ci) { rb = b; break; }   // last occurrence wins
    }
    remap[e] = rb;
}

// ---- K5a: partial[z][c][d] += sum_{j in chunk} relu(new_mem[ci[c,j]][d]) ----
__global__ void anchors_partial_kernel(const int* __restrict__ class_index,
                                       const int* __restrict__ remap,
                                       const float* __restrict__ mem_s,
                                       const float* __restrict__ mem_t,
                                       const float* __restrict__ upd,
                                       float* __restrict__ partial) // [2][NCLS*FEAT]
{
    const int z     = blockIdx.z;
    const int c     = blockIdx.y;
    const int chunk = blockIdx.x;
    const int d     = threadIdx.x;  // 128
    const float* mem = z == 0 ? mem_s : mem_t;
    const float* u   = upd + (size_t)z * (B * FEAT);
    float acc = 0.0f;
    #pragma unroll 4
    for (int j = chunk * CS; j < chunk * CS + CS; ++j) {
        const int e = c * PER + j;
        const int ci = class_index[e];
        const int rb = remap[e];
        const float* row = (rb >= 0) ? (u + rb * FEAT) : (mem + (size_t)ci * FEAT);
        const float v = row[d];
        acc += v > 0.0f ? v : 0.0f;
    }
    atomicAdd(&partial[(size_t)z * (NCLS * FEAT) + c * FEAT + d], acc);
}

// ---- K5b: anchors[z][c] = l2norm(partial / PER) ----
__global__ void anchors_finish_kernel(const float* __restrict__ partial,
                                      float* __restrict__ anchors)  // [2][NCLS*FEAT]
{
    const int z = blockIdx.y;
    const int c = blockIdx.x;
    const int d = threadIdx.x;  // 128
    const float meanv = partial[(size_t)z * (NCLS * FEAT) + c * FEAT + d]
                        * (1.0f / (float)PER);
    __shared__ float red[128];
    red[d] = meanv * meanv;
    __syncthreads();
    for (int s = 64; s > 0; s >>= 1) {
        if (d < s) red[d] += red[d + s];
        __syncthreads();
    }
    anchors[(size_t)z * (NCLS * FEAT) + c * FEAT + d] = meanv * (1.0f / sqrtf(red[0]));
}

// ---- K6: relation loss (softmax KL) + final CCD assembly ----
__global__ void final_kernel(const float* __restrict__ fsn,
                             const float* __restrict__ ftn,
                             const float* __restrict__ anchors,
                             const float* __restrict__ acc,
                             float* __restrict__ d_out)
{
    __shared__ float sa[NCLS * FEAT];
    __shared__ float ta[NCLS * FEAT];
    const int tid = threadIdx.x;  // 64 threads
    for (int i = tid; i < NCLS * FEAT; i += 64) {
        sa[i] = anchors[i];
        ta[i] = anchors[NCLS * FEAT + i];
    }
    __syncthreads();

    const int b = tid;
    float srel[NCLS], trel[NCLS];
    for (int j = 0; j < NCLS; ++j) { srel[j] = 0.0f; trel[j] = 0.0f; }
    for (int d = 0; d < FEAT; ++d) {
        const float fs = fsn[b * FEAT + d];
        const float ft = ftn[b * FEAT + d];
        #pragma unroll
        for (int j = 0; j < NCLS; ++j) {
            srel[j] = fmaf(fs, sa[j * FEAT + d], srel[j]);
            trel[j] = fmaf(ft, ta[j * FEAT + d], trel[j]);
        }
    }
    const float inv_t = 1.0f / 0.07f;
    float smax = -1e30f, tmax = -1e30f;
    for (int j = 0; j < NCLS; ++j) {
        srel[j] *= inv_t; trel[j] *= inv_t;
        smax = fmaxf(smax, srel[j]);
        tmax = fmaxf(tmax, trel[j]);
    }
    float ssum = 0.0f, tsum = 0.0f;
    float texp[NCLS];
    for (int j = 0; j < NCLS; ++j) {
        ssum += expf(srel[j] - smax);
        texp[j] = expf(trel[j] - tmax);
        tsum += texp[j];
    }
    const float lse_s = logf(ssum);
    float contrib = 0.0f;
    for (int j = 0; j < NCLS; ++j) {
        const float tgt = texp[j] / tsum;
        const float log_in = srel[j] - smax - lse_s;   // log_softmax
        contrib += tgt * (logf(tgt + 1e-30f) - log_in);
    }
    for (int off = 32; off > 0; off >>= 1) contrib += __shfl_down(contrib, off);
    if (tid == 0) {
        d_out[1] = contrib / (float)B;
        d_out[0] = -(acc[0] + acc[1]) / (float)(B * P);
    }
}

extern "C" void kernel_launch(void* const* d_in, const int* in_sizes, int n_in,
                              void* d_out_v, int out_size, void* d_ws, size_t ws_size,
                              hipStream_t stream)
{
    const float* f_s = (const float*)d_in[0];
    const float* f_t = (const float*)d_in[1];
    const int*   idx = (const int*)d_in[2];
    /* d_in[3] batch_label: unused by reference */
    const int*   class_index = (const int*)d_in[4];
    /* d_in[5] num_pos == 4 (hardcoded) */
    const int*   contrast_idx = (const int*)d_in[6];
    const float* W_s = (const float*)d_in[7];
    const float* b_s = (const float*)d_in[8];
    const float* W_t = (const float*)d_in[9];
    const float* b_t = (const float*)d_in[10];
    const float* mem_s = (const float*)d_in[11];
    const float* mem_t = (const float*)d_in[12];

    float* out    = (float*)d_out_v;
    float* out_fs = out + 2;               // f_s output (64*128)
    float* out_ft = out + 2 + B * FEAT;    // f_t output

    // workspace layout (floats)
    float* ws      = (float*)d_ws;
    float* out_raw = ws;                          // 2 * B*PK   = 1,049,088
    float* Ssum    = out_raw + 2 * (B * PK);      // 2
    float* acc     = Ssum + 2;                    // 2
    float* upd     = acc + 2;                     // 2 * B*FEAT = 16,384
    float* anchors = upd + 2 * (B * FEAT);        // 2 * NCLS*FEAT = 1,792
    float* partial = anchors + 2 * (NCLS * FEAT); // 2 * NCLS*FEAT = 1,792
    int*   remap   = (int*)(partial + 2 * (NCLS * FEAT));  // 7,000 ints

    // zero Ssum[2] + acc[2] + partial[1792]
    hipMemsetAsync(Ssum, 0, 4 * sizeof(float), stream);
    hipMemsetAsync(partial, 0, 2 * NCLS * FEAT * sizeof(float), stream);

    dim3 g1(B, 2);
    gemm_norm_kernel<<<g1, 256, 0, stream>>>(f_s, f_t, W_s, b_s, W_t, b_t,
                                             out_fs, out_ft);
    dim3 g2((PK + TCHUNK - 1) / TCHUNK, B, 2);   // 17 x 64 x 2
    dots_kernel<<<g2, 256, 0, stream>>>(out_fs, out_ft, contrast_idx,
                                        mem_s, mem_t, out_raw, Ssum);
    dim3 g3(256, 2);
    ccd_loss_kernel<<<g3, 256, 0, stream>>>(out_raw, Ssum, acc);
    dim3 g4(B, 2);
    upd_kernel<<<g4, 128, 0, stream>>>(out_fs, out_ft, idx, mem_s, mem_t, upd);
    remap_kernel<<<(NCLS * PER + 255) / 256, 256, 0, stream>>>(class_index, idx, remap);
    dim3 g5a(JCHUNKS, NCLS, 2);
    anchors_partial_kernel<<<g5a, 128, 0, stream>>>(class_index, remap,
                                                    mem_s, mem_t, upd, partial);
    dim3 g5b(NCLS, 2);
    anchors_finish_kernel<<<g5b, 128, 0, stream>>>(partial, anchors);
    final_kernel<<<1, 64, 0, stream>>>(out_fs, out_ft, anchors, acc, out);
}

// Round 7
// 185.014 us; speedup vs baseline: 1.9983x; 1.1671x over previous
//
#include <hip/hip_runtime.h>
#include <math.h>
#include <stdint.h>

#define B 64
#define SDIM 2048
#define FEAT 128
#define P 4
#define PK 8196
#define NCLS 7
#define PER 1000
#define NDATA 100000
#define EPSC 1e-7f
#define M_PN 0.08192f   /* (PK-P)/NDATA = 8192/100000 */
#define JCHUNKS 50
#define CS (PER / JCHUNKS)   /* 20 rows per block */
#define TILE 16              /* rows per LDS buffer */
#define WCHUNK 512           /* rows per block (1 wave) */
#define NT (WCHUNK / TILE)   /* 32 tiles */

// async global->LDS, 16B per lane, LDS dest = wave-uniform base + lane*16
#define GLL16(gp, lp) \
    __builtin_amdgcn_global_load_lds( \
        (__attribute__((address_space(1))) void*)(uintptr_t)(gp), \
        (__attribute__((address_space(3))) void*)(lp), 16, 0, 0)

// ---------------- K1: f = l2norm(f @ W + b) for both s and t ----------------
__global__ void gemm_norm_kernel(const float* __restrict__ f_s,
                                 const float* __restrict__ f_t,
                                 const float* __restrict__ W_s,
                                 const float* __restrict__ b_s,
                                 const float* __restrict__ W_t,
                                 const float* __restrict__ b_t,
                                 float* __restrict__ out_fs,
                                 float* __restrict__ out_ft)
{
    const int row = blockIdx.x;
    const int z   = blockIdx.y;
    const float* f    = z == 0 ? f_s : f_t;
    const float* W    = z == 0 ? W_s : W_t;
    const float* bias = z == 0 ? b_s : b_t;
    float* out        = z == 0 ? out_fs : out_ft;

    __shared__ __align__(16) float frow[SDIM];
    const int t  = threadIdx.x;        // 0..255
    const int d  = t & 127;
    const int kh = t >> 7;             // 0/1
    for (int k = t; k < SDIM; k += 256) frow[k] = f[row * SDIM + k];
    __syncthreads();

    float acc = 0.0f;
    const int k0 = kh * (SDIM / 2);
    for (int k = k0; k < k0 + SDIM / 2; ++k)
        acc = fmaf(frow[k], W[k * FEAT + d], acc);

    __shared__ float part[2][128];
    part[kh][d] = acc;
    __syncthreads();

    const float a = part[0][d] + part[1][d] + bias[d];

    __shared__ float red[256];
    red[t] = (t < 128) ? a * a : 0.0f;
    __syncthreads();
    for (int s = 128; s > 0; s >>= 1) {
        if (t < s) red[t] += red[t + s];
        __syncthreads();
    }
    if (t < 128) out[row * FEAT + t] = a * (1.0f / sqrtf(red[0]));
}

// ---- K2: out[z][b][k] = exp(dot(mem[ci], f[b]) / T), plus total sum S[z] ----
// 1 wave/block. global_load_lds direct staging (no VGPR round-trip), two
// 8KB buffers, counted s_waitcnt vmcnt(8) so 8 loads (8KB) stay in flight
// at all times. Swizzle applied on the GLOBAL source side (rule #21):
// LDS[r][s] holds row chunk (s ^ (r&7)); reads use slot g^(r&7).
__global__ __launch_bounds__(64)
void dots_kernel(const float* __restrict__ fsn,
                 const float* __restrict__ ftn,
                 const int*   __restrict__ contrast_idx,
                 const float* __restrict__ mem_s,
                 const float* __restrict__ mem_t,
                 float* __restrict__ out_raw,   // [2][B*PK]
                 float* __restrict__ Ssum)      // [2]
{
    const int z = blockIdx.z;
    const int b = blockIdx.y;
    const int l = threadIdx.x;         // 0..63
    const int kchunk = blockIdx.x * WCHUNK;

    const float* f   = (z == 0 ? fsn : ftn) + b * FEAT;
    const float* mem = (z == 0 ? mem_t : mem_s);   // NOTE the cross pairing

    __shared__ __align__(16) float rows[2][TILE * FEAT];  // 2 x 8 KB
    __shared__ __align__(16) float fl[FEAT];              // 512 B (aligned f copy)
    __shared__ int cis[WCHUNK];                           // 2 KB

    // stage f (out_fs base is only 8B-aligned -> scalar loads here) and cis
    fl[l]      = f[l];
    fl[l + 64] = f[l + 64];
    for (int i = l; i < WCHUNK; i += 64) {
        const int k = kchunk + i;
        cis[i] = contrast_idx[(size_t)b * PK + (k < PK ? k : PK - 1)];
    }
    __syncthreads();

    const int q   = l >> 4;            // quarter 0..3 (compute)
    const int r_c = l & 15;            // row this lane computes
    const int xk  = r_c & 7;           // read-side swizzle key
    const int rh  = l >> 5;            // staging row parity
    const int sl  = l & 31;            // staging float4 slot

    // loop-invariant f fragments in NAMED registers (rule #20)
    const float4* fg = (const float4*)fl;
    const float4 f0 = fg[q * 8 + 0], f1 = fg[q * 8 + 1];
    const float4 f2 = fg[q * 8 + 2], f3 = fg[q * 8 + 3];
    const float4 f4 = fg[q * 8 + 4], f5 = fg[q * 8 + 5];
    const float4 f6 = fg[q * 8 + 6], f7 = fg[q * 8 + 7];

    const float inv_t = 1.0f / 0.07f;
    const size_t obase = (size_t)z * (B * PK) + (size_t)b * PK;
    float lsum = 0.0f;

    // issue 8 async loads for tile tt into buffer bf.
    // instr p covers rows 2p (lanes 0-31) and 2p+1 (lanes 32-63), LDS-linear;
    // global chunk per lane is sl ^ (row&7) (inverse swizzle on source).
#define STAGE(tt, bf) do { \
    _Pragma("unroll") \
    for (int p_ = 0; p_ < 8; ++p_) { \
        const int rr_ = 2 * p_ + rh; \
        const int ci_ = cis[(tt) * TILE + rr_]; \
        const float* g_ = mem + (size_t)ci_ * FEAT + ((sl ^ (rr_ & 7)) << 2); \
        GLL16(g_, &rows[bf][p_ * 256]); \
    } } while (0)

    STAGE(0, 0);
    int cur = 0;
    for (int t = 0; t < NT; ++t) {
        if (t + 1 < NT) {
            STAGE(t + 1, cur ^ 1);
            // tile t's 8 loads complete; next tile's 8 stay in flight
            asm volatile("s_waitcnt vmcnt(8)" ::: "memory");
        } else {
            asm volatile("s_waitcnt vmcnt(0)" ::: "memory");
        }
        __builtin_amdgcn_sched_barrier(0);

        const float* rbase = &rows[cur][r_c * FEAT];
        float dot;
        {
            const float4 m0 = *(const float4*)(rbase + (((q * 8 + 0) ^ xk) << 2));
            const float4 m1 = *(const float4*)(rbase + (((q * 8 + 1) ^ xk) << 2));
            const float4 m2 = *(const float4*)(rbase + (((q * 8 + 2) ^ xk) << 2));
            const float4 m3 = *(const float4*)(rbase + (((q * 8 + 3) ^ xk) << 2));
            const float4 m4 = *(const float4*)(rbase + (((q * 8 + 4) ^ xk) << 2));
            const float4 m5 = *(const float4*)(rbase + (((q * 8 + 5) ^ xk) << 2));
            const float4 m6 = *(const float4*)(rbase + (((q * 8 + 6) ^ xk) << 2));
            const float4 m7 = *(const float4*)(rbase + (((q * 8 + 7) ^ xk) << 2));
            dot = m0.x * f0.x;
            dot = fmaf(m0.y, f0.y, dot); dot = fmaf(m0.z, f0.z, dot); dot = fmaf(m0.w, f0.w, dot);
            dot = fmaf(m1.x, f1.x, dot); dot = fmaf(m1.y, f1.y, dot); dot = fmaf(m1.z, f1.z, dot); dot = fmaf(m1.w, f1.w, dot);
            dot = fmaf(m2.x, f2.x, dot); dot = fmaf(m2.y, f2.y, dot); dot = fmaf(m2.z, f2.z, dot); dot = fmaf(m2.w, f2.w, dot);
            dot = fmaf(m3.x, f3.x, dot); dot = fmaf(m3.y, f3.y, dot); dot = fmaf(m3.z, f3.z, dot); dot = fmaf(m3.w, f3.w, dot);
            dot = fmaf(m4.x, f4.x, dot); dot = fmaf(m4.y, f4.y, dot); dot = fmaf(m4.z, f4.z, dot); dot = fmaf(m4.w, f4.w, dot);
            dot = fmaf(m5.x, f5.x, dot); dot = fmaf(m5.y, f5.y, dot); dot = fmaf(m5.z, f5.z, dot); dot = fmaf(m5.w, f5.w, dot);
            dot = fmaf(m6.x, f6.x, dot); dot = fmaf(m6.y, f6.y, dot); dot = fmaf(m6.z, f6.z, dot); dot = fmaf(m6.w, f6.w, dot);
            dot = fmaf(m7.x, f7.x, dot); dot = fmaf(m7.y, f7.y, dot); dot = fmaf(m7.z, f7.z, dot); dot = fmaf(m7.w, f7.w, dot);
        }
        // combine the 4 quarters (lanes r_c, r_c+16, r_c+32, r_c+48)
        dot += __shfl_xor(dot, 16);
        dot += __shfl_xor(dot, 32);

        const int krow = kchunk + t * TILE + r_c;
        if (q == 0 && krow < PK) {
            const float val = expf(dot * inv_t);
            out_raw[obase + krow] = val;
            lsum += val;
        }
        cur ^= 1;
    }
#undef STAGE

    // reduce lsum over lanes 0..15 (others hold 0), one atomic per wave
    lsum += __shfl_xor(lsum, 8);
    lsum += __shfl_xor(lsum, 4);
    lsum += __shfl_xor(lsum, 2);
    lsum += __shfl_xor(lsum, 1);
    if (l == 0) atomicAdd(&Ssum[z], lsum);
}

// ---- K3: accumulate acc[z] = sum logD1 + P * sum logD0 (weighted) ----
__global__ void ccd_loss_kernel(const float* __restrict__ out_raw,
                                const float* __restrict__ Ssum,
                                float* __restrict__ acc)   // [2]
{
    const int z = blockIdx.y;
    const float S = Ssum[z];
    // normalized v = out * c ; c = B*PK / (S * NDATA)
    const float c = ((float)(B * PK)) / (S * (float)NDATA);

    const int total = B * PK;
    float contrib = 0.0f;
    for (int i = blockIdx.x * blockDim.x + threadIdx.x; i < total;
         i += gridDim.x * blockDim.x) {
        const float v = out_raw[(size_t)z * total + i] * c;
        const int k = i % PK;
        if (k < P) {
            contrib += logf(v / (v + M_PN + EPSC));
        } else {
            contrib += (float)P * logf(M_PN / (v + M_PN + EPSC));
        }
    }
    __shared__ float red[256];
    red[threadIdx.x] = contrib;
    __syncthreads();
    for (int s = 128; s > 0; s >>= 1) {
        if (threadIdx.x < s) red[threadIdx.x] += red[threadIdx.x + s];
        __syncthreads();
    }
    if (threadIdx.x == 0) atomicAdd(&acc[z], red[0]);
}

// ---- K4: upd[z][b] = l2norm(mem[idx[b]]*0.5 + f[b]*0.5) ----
__global__ void upd_kernel(const float* __restrict__ fsn,
                           const float* __restrict__ ftn,
                           const int*   __restrict__ idx,
                           const float* __restrict__ mem_s,
                           const float* __restrict__ mem_t,
                           float* __restrict__ upd)   // [2][B*FEAT]
{
    const int z = blockIdx.y;
    const int b = blockIdx.x;
    const int d = threadIdx.x;  // 128
    const float* mem = z == 0 ? mem_s : mem_t;
    const float* f   = z == 0 ? fsn : ftn;
    const int i = idx[b];
    const float v = mem[(size_t)i * FEAT + d] * 0.5f + f[b * FEAT + d] * 0.5f;
    __shared__ float red[128];
    red[d] = v * v;
    __syncthreads();
    for (int s = 64; s > 0; s >>= 1) {
        if (d < s) red[d] += red[d + s];
        __syncthreads();
    }
    upd[(size_t)z * (B * FEAT) + b * FEAT + d] = v * (1.0f / sqrtf(red[0]));
}

// ---- K4b: remap[e] = last b with idx[b]==class_index[e], else -1 ----
__global__ void remap_kernel(const int* __restrict__ class_index,
                             const int* __restrict__ idx,
                             int* __restrict__ remap)
{
    const int e = blockIdx.x * 256 + threadIdx.x;
    if (e >= NCLS * PER) return;
    const int ci = class_index[e];
    int rb = -1;
    for (int b = B - 1; b >= 0; --b) {
        if (idx[b] == ci) { rb = b; break; }   // last occurrence wins
    }
    remap[e] = rb;
}

// ---- K5a: partial[z][c][d] += sum_{j in chunk} relu(new_mem[ci[c,j]][d]) ----
__global__ void anchors_partial_kernel(const int* __restrict__ class_index,
                                       const int* __restrict__ remap,
                                       const float* __restrict__ mem_s,
                                       const float* __restrict__ mem_t,
                                       const float* __restrict__ upd,
                                       float* __restrict__ partial) // [2][NCLS*FEAT]
{
    const int z     = blockIdx.z;
    const int c     = blockIdx.y;
    const int chunk = blockIdx.x;
    const int d     = threadIdx.x;  // 128
    const float* mem = z == 0 ? mem_s : mem_t;
    const float* u   = upd + (size_t)z * (B * FEAT);
    float acc = 0.0f;
    #pragma unroll 4
    for (int j = chunk * CS; j < chunk * CS + CS; ++j) {
        const int e = c * PER + j;
        const int ci = class_index[e];
        const int rb = remap[e];
        const float* row = (rb >= 0) ? (u + rb * FEAT) : (mem + (size_t)ci * FEAT);
        const float v = row[d];
        acc += v > 0.0f ? v : 0.0f;
    }
    atomicAdd(&partial[(size_t)z * (NCLS * FEAT) + c * FEAT + d], acc);
}

// ---- K5b: anchors[z][c] = l2norm(partial / PER) ----
__global__ void anchors_finish_kernel(const float* __restrict__ partial,
                                      float* __restrict__ anchors)  // [2][NCLS*FEAT]
{
    const int z = blockIdx.y;
    const int c = blockIdx.x;
    const int d = threadIdx.x;  // 128
    const float meanv = partial[(size_t)z * (NCLS * FEAT) + c * FEAT + d]
                        * (1.0f / (float)PER);
    __shared__ float red[128];
    red[d] = meanv * meanv;
    __syncthreads();
    for (int s = 64; s > 0; s >>= 1) {
        if (d < s) red[d] += red[d + s];
        __syncthreads();
    }
    anchors[(size_t)z * (NCLS * FEAT) + c * FEAT + d] = meanv * (1.0f / sqrtf(red[0]));
}

// ---- K6: relation loss (softmax KL) + final CCD assembly ----
__global__ void final_kernel(const float* __restrict__ fsn,
                             const float* __restrict__ ftn,
                             const float* __restrict__ anchors,
                             const float* __restrict__ acc,
                             float* __restrict__ d_out)
{
    __shared__ float sa[NCLS * FEAT];
    __shared__ float ta[NCLS * FEAT];
    const int tid = threadIdx.x;  // 64 threads
    for (int i = tid; i < NCLS * FEAT; i += 64) {
        sa[i] = anchors[i];
        ta[i] = anchors[NCLS * FEAT + i];
    }
    __syncthreads();

    const int b = tid;
    float srel[NCLS], trel[NCLS];
    for (int j = 0; j < NCLS; ++j) { srel[j] = 0.0f; trel[j] = 0.0f; }
    for (int d = 0; d < FEAT; ++d) {
        const float fs = fsn[b * FEAT + d];
        const float ft = ftn[b * FEAT + d];
        #pragma unroll
        for (int j = 0; j < NCLS; ++j) {
            srel[j] = fmaf(fs, sa[j * FEAT + d], srel[j]);
            trel[j] = fmaf(ft, ta[j * FEAT + d], trel[j]);
        }
    }
    const float inv_t = 1.0f / 0.07f;
    float smax = -1e30f, tmax = -1e30f;
    for (int j = 0; j < NCLS; ++j) {
        srel[j] *= inv_t; trel[j] *= inv_t;
        smax = fmaxf(smax, srel[j]);
        tmax = fmaxf(tmax, trel[j]);
    }
    float ssum = 0.0f, tsum = 0.0f;
    float texp[NCLS];
    for (int j = 0; j < NCLS; ++j) {
        ssum += expf(srel[j] - smax);
        texp[j] = expf(trel[j] - tmax);
        tsum += texp[j];
    }
    const float lse_s = logf(ssum);
    float contrib = 0.0f;
    for (int j = 0; j < NCLS; ++j) {
        const float tgt = texp[j] / tsum;
        const float log_in = srel[j] - smax - lse_s;   // log_softmax
        contrib += tgt * (logf(tgt + 1e-30f) - log_in);
    }
    for (int off = 32; off > 0; off >>= 1) contrib += __shfl_down(contrib, off);
    if (tid == 0) {
        d_out[1] = contrib / (float)B;
        d_out[0] = -(acc[0] + acc[1]) / (float)(B * P);
    }
}

extern "C" void kernel_launch(void* const* d_in, const int* in_sizes, int n_in,
                              void* d_out_v, int out_size, void* d_ws, size_t ws_size,
                              hipStream_t stream)
{
    const float* f_s = (const float*)d_in[0];
    const float* f_t = (const float*)d_in[1];
    const int*   idx = (const int*)d_in[2];
    /* d_in[3] batch_label: unused by reference */
    const int*   class_index = (const int*)d_in[4];
    /* d_in[5] num_pos == 4 (hardcoded) */
    const int*   contrast_idx = (const int*)d_in[6];
    const float* W_s = (const float*)d_in[7];
    const float* b_s = (const float*)d_in[8];
    const float* W_t = (const float*)d_in[9];
    const float* b_t = (const float*)d_in[10];
    const float* mem_s = (const float*)d_in[11];
    const float* mem_t = (const float*)d_in[12];

    float* out    = (float*)d_out_v;
    float* out_fs = out + 2;               // f_s output (64*128)
    float* out_ft = out + 2 + B * FEAT;    // f_t output

    // workspace layout (floats)
    float* ws      = (float*)d_ws;
    float* out_raw = ws;                          // 2 * B*PK   = 1,049,088
    float* Ssum    = out_raw + 2 * (B * PK);      // 2
    float* acc     = Ssum + 2;                    // 2
    float* upd     = acc + 2;                     // 2 * B*FEAT = 16,384
    float* anchors = upd + 2 * (B * FEAT);        // 2 * NCLS*FEAT = 1,792
    float* partial = anchors + 2 * (NCLS * FEAT); // 2 * NCLS*FEAT = 1,792
    int*   remap   = (int*)(partial + 2 * (NCLS * FEAT));  // 7,000 ints

    // zero Ssum[2] + acc[2] + partial[1792]
    hipMemsetAsync(Ssum, 0, 4 * sizeof(float), stream);
    hipMemsetAsync(partial, 0, 2 * NCLS * FEAT * sizeof(float), stream);

    dim3 g1(B, 2);
    gemm_norm_kernel<<<g1, 256, 0, stream>>>(f_s, f_t, W_s, b_s, W_t, b_t,
                                             out_fs, out_ft);
    dim3 g2((PK + WCHUNK - 1) / WCHUNK, B, 2);   // 17 x 64 x 2
    dots_kernel<<<g2, 64, 0, stream>>>(out_fs, out_ft, contrast_idx,
                                       mem_s, mem_t, out_raw, Ssum);
    dim3 g3(256, 2);
    ccd_loss_kernel<<<g3, 256, 0, stream>>>(out_raw, Ssum, acc);
    dim3 g4(B, 2);
    upd_kernel<<<g4, 128, 0, stream>>>(out_fs, out_ft, idx, mem_s, mem_t, upd);
    remap_kernel<<<(NCLS * PER + 255) / 256, 256, 0, stream>>>(class_index, idx, remap);
    dim3 g5a(JCHUNKS, NCLS, 2);
    anchors_partial_kernel<<<g5a, 128, 0, stream>>>(class_index, remap,
                                                    mem_s, mem_t, upd, partial);
    dim3 g5b(NCLS, 2);
    anchors_finish_kernel<<<g5b, 128, 0, stream>>>(partial, anchors);
    final_kernel<<<1, 64, 0, stream>>>(out_fs, out_ft, anchors, acc, out);
}

// Round 8
// 184.092 us; speedup vs baseline: 2.0083x; 1.0050x over previous
//
#include <hip/hip_runtime.h>
#include <math.h>
#include <stdint.h>

#define B 64
#define SDIM 2048
#define FEAT 128
#define P 4
#define PK 8196
#define NCLS 7
#define PER 1000
#define NDATA 100000
#define EPSC 1e-7f
#define M_PN 0.08192f   /* (PK-P)/NDATA = 8192/100000 */
#define JCHUNKS 50
#define CS (PER / JCHUNKS)   /* 20 rows per block */

/* D-table GEMM config */
#define GR 128               /* rows per block */
#define KC 32                /* k-chunk */
#define DTSZ (64 * NDATA)    /* floats per side: 6,400,000 */
#define KSPLIT 4
#define KSEG 2049            /* 4*2049 = 8196 = PK */

/* fallback (R7) dots config */
#define TILE 16
#define WCHUNK 512
#define NT (WCHUNK / TILE)

#define GLL16(gp, lp) \
    __builtin_amdgcn_global_load_lds( \
        (__attribute__((address_space(1))) void*)(uintptr_t)(gp), \
        (__attribute__((address_space(3))) void*)(lp), 16, 0, 0)

// ---------------- K1: f = l2norm(f @ W + b) for both s and t ----------------
// Writes the (8B-aligned) d_out slot AND a 16B-aligned ws copy for the GEMM.
__global__ void gemm_norm_kernel(const float* __restrict__ f_s,
                                 const float* __restrict__ f_t,
                                 const float* __restrict__ W_s,
                                 const float* __restrict__ b_s,
                                 const float* __restrict__ W_t,
                                 const float* __restrict__ b_t,
                                 float* __restrict__ out_fs,
                                 float* __restrict__ out_ft,
                                 float* __restrict__ fsw,
                                 float* __restrict__ ftw)
{
    const int row = blockIdx.x;
    const int z   = blockIdx.y;
    const float* f    = z == 0 ? f_s : f_t;
    const float* W    = z == 0 ? W_s : W_t;
    const float* bias = z == 0 ? b_s : b_t;
    float* out        = z == 0 ? out_fs : out_ft;
    float* fw         = z == 0 ? fsw : ftw;

    __shared__ __align__(16) float frow[SDIM];
    const int t  = threadIdx.x;        // 0..255
    const int d  = t & 127;
    const int kh = t >> 7;             // 0/1
    for (int k = t; k < SDIM; k += 256) frow[k] = f[row * SDIM + k];
    __syncthreads();

    float acc = 0.0f;
    const int k0 = kh * (SDIM / 2);
    for (int k = k0; k < k0 + SDIM / 2; ++k)
        acc = fmaf(frow[k], W[k * FEAT + d], acc);

    __shared__ float part[2][128];
    part[kh][d] = acc;
    __syncthreads();

    const float a = part[0][d] + part[1][d] + bias[d];

    __shared__ float red[256];
    red[t] = (t < 128) ? a * a : 0.0f;
    __syncthreads();
    for (int s = 128; s > 0; s >>= 1) {
        if (t < s) red[t] += red[t + s];
        __syncthreads();
    }
    if (t < 128) {
        const float v = a * (1.0f / sqrtf(red[0]));
        out[row * FEAT + t] = v;
        fw[row * FEAT + t]  = v;
    }
}

// ---- K2a: DT[b][row] = dot(mem[row], fW[b])  (tall-skinny fp32 GEMM) ----
// 256 thr; block tile 128 rows x 64 b; thread tile 4 rows (stride 32) x 8 b.
// A chunk in swizzled LDS (slot ^= row&7), F full-K in LDS.
__global__ __launch_bounds__(256)
void dgemm_kernel(const float* __restrict__ fW,   // [64][128], 16B-aligned
                  const float* __restrict__ mem,  // [NDATA][128]
                  float* __restrict__ DT)         // [64][NDATA]
{
    const int rbase = blockIdx.x * GR;
    const int t  = threadIdx.x;
    const int rg = t & 31;
    const int bg = t >> 5;             // 0..7

    __shared__ __align__(16) float4 A4[GR * 8];      // 16 KB, slot-swizzled
    __shared__ __align__(16) float  Fl[64 * FEAT];   // 32 KB

    // stage F (coalesced float4)
    {
        const float4* src = (const float4*)fW;
        float4* dst = (float4*)Fl;
        #pragma unroll
        for (int c = 0; c < 8; ++c) dst[t + 256 * c] = src[t + 256 * c];
    }

    float acc[4][8];
    #pragma unroll
    for (int i = 0; i < 4; ++i)
        #pragma unroll
        for (int j = 0; j < 8; ++j) acc[i][j] = 0.0f;

    const int srow = t >> 1;                       // staging row 0..127
    const int grow = min(rbase + srow, NDATA - 1); // clamped
    const float* gsrc = mem + (size_t)grow * FEAT;
    const int sh  = (t & 1) * 4;                   // slot base 0/4
    const int swz = srow & 7;
    const int xk  = rg & 7;                        // == (rg+i*32)&7 for all i
    const float4* F4 = (const float4*)Fl;

    for (int kc = 0; kc < FEAT; kc += KC) {
        __syncthreads();                           // protect A4 readers
        #pragma unroll
        for (int c = 0; c < 4; ++c) {
            const int s = sh + c;
            A4[srow * 8 + (s ^ swz)] = *(const float4*)(gsrc + kc + s * 4);
        }
        __syncthreads();

        #pragma unroll
        for (int s4 = 0; s4 < 8; ++s4) {
            const float4 a0 = A4[(rg +  0) * 8 + (s4 ^ xk)];
            const float4 a1 = A4[(rg + 32) * 8 + (s4 ^ xk)];
            const float4 a2 = A4[(rg + 64) * 8 + (s4 ^ xk)];
            const float4 a3 = A4[(rg + 96) * 8 + (s4 ^ xk)];
            const int kq = (kc >> 2) + s4;
            #pragma unroll
            for (int j = 0; j < 8; ++j) {
                const float4 fv = F4[(bg * 8 + j) * 32 + kq];
                acc[0][j] = fmaf(a0.x, fv.x, acc[0][j]);
                acc[0][j] = fmaf(a0.y, fv.y, acc[0][j]);
                acc[0][j] = fmaf(a0.z, fv.z, acc[0][j]);
                acc[0][j] = fmaf(a0.w, fv.w, acc[0][j]);
                acc[1][j] = fmaf(a1.x, fv.x, acc[1][j]);
                acc[1][j] = fmaf(a1.y, fv.y, acc[1][j]);
                acc[1][j] = fmaf(a1.z, fv.z, acc[1][j]);
                acc[1][j] = fmaf(a1.w, fv.w, acc[1][j]);
                acc[2][j] = fmaf(a2.x, fv.x, acc[2][j]);
                acc[2][j] = fmaf(a2.y, fv.y, acc[2][j]);
                acc[2][j] = fmaf(a2.z, fv.z, acc[2][j]);
                acc[2][j] = fmaf(a2.w, fv.w, acc[2][j]);
                acc[3][j] = fmaf(a3.x, fv.x, acc[3][j]);
                acc[3][j] = fmaf(a3.y, fv.y, acc[3][j]);
                acc[3][j] = fmaf(a3.z, fv.z, acc[3][j]);
                acc[3][j] = fmaf(a3.w, fv.w, acc[3][j]);
            }
        }
    }

    // DT store: lanes rg consecutive -> contiguous 4B -> coalesced
    #pragma unroll
    for (int j = 0; j < 8; ++j) {
        const int b = bg * 8 + j;
        float* drow = DT + (size_t)b * NDATA + rbase + rg;
        #pragma unroll
        for (int i = 0; i < 4; ++i) {
            if (rbase + rg + i * 32 < NDATA) drow[i * 32] = acc[i][j];
        }
    }
}

// ---- K2b: out_raw[b][k] = exp(DT[b][ci[b,k]] / T), accumulate Ssum ----
__global__ void gather_kernel(const int* __restrict__ contrast_idx,
                              const float* __restrict__ DT,
                              float* __restrict__ out_raw_z,  // [B*PK]
                              float* __restrict__ Ssum_z)     // scalar
{
    const int b   = blockIdx.y;
    const int ks  = blockIdx.x;
    const int tid = threadIdx.x;
    const int k0  = ks * KSEG;
    const int kend = min(k0 + KSEG, PK);
    const float inv_t = 1.0f / 0.07f;
    const float* dtb = DT + (size_t)b * NDATA;
    float lsum = 0.0f;
    #pragma unroll 4
    for (int k = k0 + tid; k < kend; k += 256) {
        const int ci = contrast_idx[(size_t)b * PK + k];
        const float v = expf(dtb[ci] * inv_t);
        out_raw_z[(size_t)b * PK + k] = v;
        lsum += v;
    }
    __shared__ float red[256];
    red[tid] = lsum;
    __syncthreads();
    for (int s = 128; s > 0; s >>= 1) {
        if (tid < s) red[tid] += red[tid + s];
        __syncthreads();
    }
    if (tid == 0) atomicAdd(Ssum_z, red[0]);
}

// ---- FALLBACK dots (R7): used only if ws too small for the D-table ----
__global__ __launch_bounds__(64)
void dots_kernel(const float* __restrict__ fsn,
                 const float* __restrict__ ftn,
                 const int*   __restrict__ contrast_idx,
                 const float* __restrict__ mem_s,
                 const float* __restrict__ mem_t,
                 float* __restrict__ out_raw,
                 float* __restrict__ Ssum)
{
    const int z = blockIdx.z;
    const int b = blockIdx.y;
    const int l = threadIdx.x;
    const int kchunk = blockIdx.x * WCHUNK;

    const float* f   = (z == 0 ? fsn : ftn) + b * FEAT;
    const float* mem = (z == 0 ? mem_t : mem_s);

    __shared__ __align__(16) float rows[2][TILE * FEAT];
    __shared__ __align__(16) float fl[FEAT];
    __shared__ int cis[WCHUNK];

    fl[l]      = f[l];
    fl[l + 64] = f[l + 64];
    for (int i = l; i < WCHUNK; i += 64) {
        const int k = kchunk + i;
        cis[i] = contrast_idx[(size_t)b * PK + (k < PK ? k : PK - 1)];
    }
    __syncthreads();

    const int q   = l >> 4;
    const int r_c = l & 15;
    const int xk  = r_c & 7;
    const int rh  = l >> 5;
    const int sl  = l & 31;

    const float4* fg = (const float4*)fl;
    const float4 f0 = fg[q * 8 + 0], f1 = fg[q * 8 + 1];
    const float4 f2 = fg[q * 8 + 2], f3 = fg[q * 8 + 3];
    const float4 f4 = fg[q * 8 + 4], f5 = fg[q * 8 + 5];
    const float4 f6 = fg[q * 8 + 6], f7 = fg[q * 8 + 7];

    const float inv_t = 1.0f / 0.07f;
    const size_t obase = (size_t)z * (B * PK) + (size_t)b * PK;
    float lsum = 0.0f;

#define STAGE(tt, bf) do { \
    _Pragma("unroll") \
    for (int p_ = 0; p_ < 8; ++p_) { \
        const int rr_ = 2 * p_ + rh; \
        const int ci_ = cis[(tt) * TILE + rr_]; \
        const float* g_ = mem + (size_t)ci_ * FEAT + ((sl ^ (rr_ & 7)) << 2); \
        GLL16(g_, &rows[bf][p_ * 256]); \
    } } while (0)

    STAGE(0, 0);
    int cur = 0;
    for (int t = 0; t < NT; ++t) {
        if (t + 1 < NT) {
            STAGE(t + 1, cur ^ 1);
            asm volatile("s_waitcnt vmcnt(8)" ::: "memory");
        } else {
            asm volatile("s_waitcnt vmcnt(0)" ::: "memory");
        }
        __builtin_amdgcn_sched_barrier(0);

        const float* rbase = &rows[cur][r_c * FEAT];
        float dot;
        {
            const float4 m0 = *(const float4*)(rbase + (((q * 8 + 0) ^ xk) << 2));
            const float4 m1 = *(const float4*)(rbase + (((q * 8 + 1) ^ xk) << 2));
            const float4 m2 = *(const float4*)(rbase + (((q * 8 + 2) ^ xk) << 2));
            const float4 m3 = *(const float4*)(rbase + (((q * 8 + 3) ^ xk) << 2));
            const float4 m4 = *(const float4*)(rbase + (((q * 8 + 4) ^ xk) << 2));
            const float4 m5 = *(const float4*)(rbase + (((q * 8 + 5) ^ xk) << 2));
            const float4 m6 = *(const float4*)(rbase + (((q * 8 + 6) ^ xk) << 2));
            const float4 m7 = *(const float4*)(rbase + (((q * 8 + 7) ^ xk) << 2));
            dot = m0.x * f0.x;
            dot = fmaf(m0.y, f0.y, dot); dot = fmaf(m0.z, f0.z, dot); dot = fmaf(m0.w, f0.w, dot);
            dot = fmaf(m1.x, f1.x, dot); dot = fmaf(m1.y, f1.y, dot); dot = fmaf(m1.z, f1.z, dot); dot = fmaf(m1.w, f1.w, dot);
            dot = fmaf(m2.x, f2.x, dot); dot = fmaf(m2.y, f2.y, dot); dot = fmaf(m2.z, f2.z, dot); dot = fmaf(m2.w, f2.w, dot);
            dot = fmaf(m3.x, f3.x, dot); dot = fmaf(m3.y, f3.y, dot); dot = fmaf(m3.z, f3.z, dot); dot = fmaf(m3.w, f3.w, dot);
            dot = fmaf(m4.x, f4.x, dot); dot = fmaf(m4.y, f4.y, dot); dot = fmaf(m4.z, f4.z, dot); dot = fmaf(m4.w, f4.w, dot);
            dot = fmaf(m5.x, f5.x, dot); dot = fmaf(m5.y, f5.y, dot); dot = fmaf(m5.z, f5.z, dot); dot = fmaf(m5.w, f5.w, dot);
            dot = fmaf(m6.x, f6.x, dot); dot = fmaf(m6.y, f6.y, dot); dot = fmaf(m6.z, f6.z, dot); dot = fmaf(m6.w, f6.w, dot);
            dot = fmaf(m7.x, f7.x, dot); dot = fmaf(m7.y, f7.y, dot); dot = fmaf(m7.z, f7.z, dot); dot = fmaf(m7.w, f7.w, dot);
        }
        dot += __shfl_xor(dot, 16);
        dot += __shfl_xor(dot, 32);

        const int krow = kchunk + t * TILE + r_c;
        if (q == 0 && krow < PK) {
            const float val = expf(dot * inv_t);
            out_raw[obase + krow] = val;
            lsum += val;
        }
        cur ^= 1;
    }
#undef STAGE

    lsum += __shfl_xor(lsum, 8);
    lsum += __shfl_xor(lsum, 4);
    lsum += __shfl_xor(lsum, 2);
    lsum += __shfl_xor(lsum, 1);
    if (l == 0) atomicAdd(&Ssum[z], lsum);
}

// ---- K3: accumulate acc[z] = sum logD1 + P * sum logD0 (weighted) ----
__global__ void ccd_loss_kernel(const float* __restrict__ out_raw,
                                const float* __restrict__ Ssum,
                                float* __restrict__ acc)
{
    const int z = blockIdx.y;
    const float S = Ssum[z];
    const float c = ((float)(B * PK)) / (S * (float)NDATA);

    const int total = B * PK;
    float contrib = 0.0f;
    for (int i = blockIdx.x * blockDim.x + threadIdx.x; i < total;
         i += gridDim.x * blockDim.x) {
        const float v = out_raw[(size_t)z * total + i] * c;
        const int k = i % PK;
        if (k < P) {
            contrib += logf(v / (v + M_PN + EPSC));
        } else {
            contrib += (float)P * logf(M_PN / (v + M_PN + EPSC));
        }
    }
    __shared__ float red[256];
    red[threadIdx.x] = contrib;
    __syncthreads();
    for (int s = 128; s > 0; s >>= 1) {
        if (threadIdx.x < s) red[threadIdx.x] += red[threadIdx.x + s];
        __syncthreads();
    }
    if (threadIdx.x == 0) atomicAdd(&acc[z], red[0]);
}

// ---- K4: upd[z][b] = l2norm(mem[idx[b]]*0.5 + f[b]*0.5) ----
__global__ void upd_kernel(const float* __restrict__ fsn,
                           const float* __restrict__ ftn,
                           const int*   __restrict__ idx,
                           const float* __restrict__ mem_s,
                           const float* __restrict__ mem_t,
                           float* __restrict__ upd)
{
    const int z = blockIdx.y;
    const int b = blockIdx.x;
    const int d = threadIdx.x;
    const float* mem = z == 0 ? mem_s : mem_t;
    const float* f   = z == 0 ? fsn : ftn;
    const int i = idx[b];
    const float v = mem[(size_t)i * FEAT + d] * 0.5f + f[b * FEAT + d] * 0.5f;
    __shared__ float red[128];
    red[d] = v * v;
    __syncthreads();
    for (int s = 64; s > 0; s >>= 1) {
        if (d < s) red[d] += red[d + s];
        __syncthreads();
    }
    upd[(size_t)z * (B * FEAT) + b * FEAT + d] = v * (1.0f / sqrtf(red[0]));
}

// ---- K4b: remap[e] = last b with idx[b]==class_index[e], else -1 ----
__global__ void remap_kernel(const int* __restrict__ class_index,
                             const int* __restrict__ idx,
                             int* __restrict__ remap)
{
    const int e = blockIdx.x * 256 + threadIdx.x;
    if (e >= NCLS * PER) return;
    const int ci = class_index[e];
    int rb = -1;
    for (int b = B - 1; b >= 0; --b) {
        if (idx[b] == ci) { rb = b; break; }
    }
    remap[e] = rb;
}

// ---- K5a ----
__global__ void anchors_partial_kernel(const int* __restrict__ class_index,
                                       const int* __restrict__ remap,
                                       const float* __restrict__ mem_s,
                                       const float* __restrict__ mem_t,
                                       const float* __restrict__ upd,
                                       float* __restrict__ partial)
{
    const int z     = blockIdx.z;
    const int c     = blockIdx.y;
    const int chunk = blockIdx.x;
    const int d     = threadIdx.x;
    const float* mem = z == 0 ? mem_s : mem_t;
    const float* u   = upd + (size_t)z * (B * FEAT);
    float acc = 0.0f;
    #pragma unroll 4
    for (int j = chunk * CS; j < chunk * CS + CS; ++j) {
        const int e = c * PER + j;
        const int ci = class_index[e];
        const int rb = remap[e];
        const float* row = (rb >= 0) ? (u + rb * FEAT) : (mem + (size_t)ci * FEAT);
        const float v = row[d];
        acc += v > 0.0f ? v : 0.0f;
    }
    atomicAdd(&partial[(size_t)z * (NCLS * FEAT) + c * FEAT + d], acc);
}

// ---- K5b ----
__global__ void anchors_finish_kernel(const float* __restrict__ partial,
                                      float* __restrict__ anchors)
{
    const int z = blockIdx.y;
    const int c = blockIdx.x;
    const int d = threadIdx.x;
    const float meanv = partial[(size_t)z * (NCLS * FEAT) + c * FEAT + d]
                        * (1.0f / (float)PER);
    __shared__ float red[128];
    red[d] = meanv * meanv;
    __syncthreads();
    for (int s = 64; s > 0; s >>= 1) {
        if (d < s) red[d] += red[d + s];
        __syncthreads();
    }
    anchors[(size_t)z * (NCLS * FEAT) + c * FEAT + d] = meanv * (1.0f / sqrtf(red[0]));
}

// ---- K6 ----
__global__ void final_kernel(const float* __restrict__ fsn,
                             const float* __restrict__ ftn,
                             const float* __restrict__ anchors,
                             const float* __restrict__ acc,
                             float* __restrict__ d_out)
{
    __shared__ float sa[NCLS * FEAT];
    __shared__ float ta[NCLS * FEAT];
    const int tid = threadIdx.x;
    for (int i = tid; i < NCLS * FEAT; i += 64) {
        sa[i] = anchors[i];
        ta[i] = anchors[NCLS * FEAT + i];
    }
    __syncthreads();

    const int b = tid;
    float srel[NCLS], trel[NCLS];
    for (int j = 0; j < NCLS; ++j) { srel[j] = 0.0f; trel[j] = 0.0f; }
    for (int d = 0; d < FEAT; ++d) {
        const float fs = fsn[b * FEAT + d];
        const float ft = ftn[b * FEAT + d];
        #pragma unroll
        for (int j = 0; j < NCLS; ++j) {
            srel[j] = fmaf(fs, sa[j * FEAT + d], srel[j]);
            trel[j] = fmaf(ft, ta[j * FEAT + d], trel[j]);
        }
    }
    const float inv_t = 1.0f / 0.07f;
    float smax = -1e30f, tmax = -1e30f;
    for (int j = 0; j < NCLS; ++j) {
        srel[j] *= inv_t; trel[j] *= inv_t;
        smax = fmaxf(smax, srel[j]);
        tmax = fmaxf(tmax, trel[j]);
    }
    float ssum = 0.0f, tsum = 0.0f;
    float texp[NCLS];
    for (int j = 0; j < NCLS; ++j) {
        ssum += expf(srel[j] - smax);
        texp[j] = expf(trel[j] - tmax);
        tsum += texp[j];
    }
    const float lse_s = logf(ssum);
    float contrib = 0.0f;
    for (int j = 0; j < NCLS; ++j) {
        const float tgt = texp[j] / tsum;
        const float log_in = srel[j] - smax - lse_s;
        contrib += tgt * (logf(tgt + 1e-30f) - log_in);
    }
    for (int off = 32; off > 0; off >>= 1) contrib += __shfl_down(contrib, off);
    if (tid == 0) {
        d_out[1] = contrib / (float)B;
        d_out[0] = -(acc[0] + acc[1]) / (float)(B * P);
    }
}

extern "C" void kernel_launch(void* const* d_in, const int* in_sizes, int n_in,
                              void* d_out_v, int out_size, void* d_ws, size_t ws_size,
                              hipStream_t stream)
{
    const float* f_s = (const float*)d_in[0];
    const float* f_t = (const float*)d_in[1];
    const int*   idx = (const int*)d_in[2];
    const int*   class_index = (const int*)d_in[4];
    const int*   contrast_idx = (const int*)d_in[6];
    const float* W_s = (const float*)d_in[7];
    const float* b_s = (const float*)d_in[8];
    const float* W_t = (const float*)d_in[9];
    const float* b_t = (const float*)d_in[10];
    const float* mem_s = (const float*)d_in[11];
    const float* mem_t = (const float*)d_in[12];

    float* out    = (float*)d_out_v;
    float* out_fs = out + 2;
    float* out_ft = out + 2 + B * FEAT;

    float* ws = (float*)d_ws;
    const size_t fl = ws_size / sizeof(float);
    const size_t REST = 2 * (size_t)B * PK   /* out_raw */
                      + 2 * 64 * FEAT        /* fsw+ftw  */
                      + 2 * B * FEAT         /* upd      */
                      + 4 * NCLS * FEAT      /* anchors+partial */
                      + NCLS * PER           /* remap    */
                      + 64;                  /* Ssum/acc + slack */
    const bool big   = fl >= 2 * (size_t)DTSZ + REST;
    const bool small = fl >= 1 * (size_t)DTSZ + REST;

    if (small) {
        // ---------- D-table path ----------
        float* DT0 = ws;
        float* DT1 = big ? ws + DTSZ : DT0;
        float* out_raw = (big ? ws + 2 * (size_t)DTSZ : ws + DTSZ);
        float* fsw     = out_raw + 2 * (size_t)B * PK;   // 16B-aligned
        float* ftw     = fsw + 64 * FEAT;
        float* upd     = ftw + 64 * FEAT;
        float* anchors = upd + 2 * B * FEAT;
        float* partial = anchors + 2 * NCLS * FEAT;
        float* Ssum    = partial + 2 * NCLS * FEAT;      // [2]
        float* acc     = Ssum + 2;                       // [2]
        int*   remap   = (int*)(acc + 2);

        hipMemsetAsync(Ssum, 0, 4 * sizeof(float), stream);
        hipMemsetAsync(partial, 0, 2 * NCLS * FEAT * sizeof(float), stream);

        dim3 g1(B, 2);
        gemm_norm_kernel<<<g1, 256, 0, stream>>>(f_s, f_t, W_s, b_s, W_t, b_t,
                                                 out_fs, out_ft, fsw, ftw);

        const int gblocks = (NDATA + GR - 1) / GR;   // 782
        dim3 gg(KSPLIT, B);
        if (big) {
            dgemm_kernel<<<gblocks, 256, 0, stream>>>(fsw, mem_t, DT0);
            dgemm_kernel<<<gblocks, 256, 0, stream>>>(ftw, mem_s, DT1);
            gather_kernel<<<gg, 256, 0, stream>>>(contrast_idx, DT0, out_raw, Ssum);
            gather_kernel<<<gg, 256, 0, stream>>>(contrast_idx, DT1,
                                                  out_raw + (size_t)B * PK, Ssum + 1);
        } else {
            dgemm_kernel<<<gblocks, 256, 0, stream>>>(fsw, mem_t, DT0);
            gather_kernel<<<gg, 256, 0, stream>>>(contrast_idx, DT0, out_raw, Ssum);
            dgemm_kernel<<<gblocks, 256, 0, stream>>>(ftw, mem_s, DT0);
            gather_kernel<<<gg, 256, 0, stream>>>(contrast_idx, DT0,
                                                  out_raw + (size_t)B * PK, Ssum + 1);
        }

        dim3 g3(256, 2);
        ccd_loss_kernel<<<g3, 256, 0, stream>>>(out_raw, Ssum, acc);
        dim3 g4(B, 2);
        upd_kernel<<<g4, 128, 0, stream>>>(out_fs, out_ft, idx, mem_s, mem_t, upd);
        remap_kernel<<<(NCLS * PER + 255) / 256, 256, 0, stream>>>(class_index, idx, remap);
        dim3 g5a(JCHUNKS, NCLS, 2);
        anchors_partial_kernel<<<g5a, 128, 0, stream>>>(class_index, remap,
                                                        mem_s, mem_t, upd, partial);
        dim3 g5b(NCLS, 2);
        anchors_finish_kernel<<<g5b, 128, 0, stream>>>(partial, anchors);
        final_kernel<<<1, 64, 0, stream>>>(out_fs, out_ft, anchors, acc, out);
    } else {
        // ---------- fallback: R7 layout & path ----------
        float* out_raw = ws;
        float* Ssum    = out_raw + 2 * (B * PK);
        float* acc     = Ssum + 2;
        float* upd     = acc + 2;
        float* anchors = upd + 2 * (B * FEAT);
        float* partial = anchors + 2 * (NCLS * FEAT);
        int*   remap   = (int*)(partial + 2 * (NCLS * FEAT));

        hipMemsetAsync(Ssum, 0, 4 * sizeof(float), stream);
        hipMemsetAsync(partial, 0, 2 * NCLS * FEAT * sizeof(float), stream);

        dim3 g1(B, 2);
        gemm_norm_kernel<<<g1, 256, 0, stream>>>(f_s, f_t, W_s, b_s, W_t, b_t,
                                                 out_fs, out_ft,
                                                 out_fs, out_ft);  // fw unused dup
        dim3 g2((PK + WCHUNK - 1) / WCHUNK, B, 2);
        dots_kernel<<<g2, 64, 0, stream>>>(out_fs, out_ft, contrast_idx,
                                           mem_s, mem_t, out_raw, Ssum);
        dim3 g3(256, 2);
        ccd_loss_kernel<<<g3, 256, 0, stream>>>(out_raw, Ssum, acc);
        dim3 g4(B, 2);
        upd_kernel<<<g4, 128, 0, stream>>>(out_fs, out_ft, idx, mem_s, mem_t, upd);
        remap_kernel<<<(NCLS * PER + 255) / 256, 256, 0, stream>>>(class_index, idx, remap);
        dim3 g5a(JCHUNKS, NCLS, 2);
        anchors_partial_kernel<<<g5a, 128, 0, stream>>>(class_index, remap,
                                                        mem_s, mem_t, upd, partial);
        dim3 g5b(NCLS, 2);
        anchors_finish_kernel<<<g5b, 128, 0, stream>>>(partial, anchors);
        final_kernel<<<1, 64, 0, stream>>>(out_fs, out_ft, anchors, acc, out);
    }
}

// Round 9
// 174.623 us; speedup vs baseline: 2.1172x; 1.0542x over previous
//
#include <hip/hip_runtime.h>
#include <math.h>
#include <stdint.h>

#define B 64
#define SDIM 2048
#define FEAT 128
#define P 4
#define PK 8196
#define NCLS 7
#define PER 1000
#define NDATA 100000
#define EPSC 1e-7f
#define M_PN 0.08192f   /* (PK-P)/NDATA = 8192/100000 */
#define JCHUNKS 50
#define CS (PER / JCHUNKS)   /* 20 rows per block */

/* D-table GEMM config */
#define GR 256               /* rows per block */
#define DTSZ (64 * NDATA)    /* floats per side: 6,400,000 */
#define KSPLIT 4
#define KSEG 2049            /* 4*2049 = 8196 = PK */
#define APAD 257             /* float4s per slot-plane (256 + 1 pad) */

/* fallback (R7) dots config */
#define TILE 16
#define WCHUNK 512
#define NT (WCHUNK / TILE)

#define GLL16(gp, lp) \
    __builtin_amdgcn_global_load_lds( \
        (__attribute__((address_space(1))) void*)(uintptr_t)(gp), \
        (__attribute__((address_space(3))) void*)(lp), 16, 0, 0)

#define FMA4(ACC, AV, FV) do { \
    (ACC) = fmaf((AV).x, (FV).x, (ACC)); \
    (ACC) = fmaf((AV).y, (FV).y, (ACC)); \
    (ACC) = fmaf((AV).z, (FV).z, (ACC)); \
    (ACC) = fmaf((AV).w, (FV).w, (ACC)); } while (0)

// ---------------- K1: f = l2norm(f @ W + b) for both s and t ----------------
__global__ void gemm_norm_kernel(const float* __restrict__ f_s,
                                 const float* __restrict__ f_t,
                                 const float* __restrict__ W_s,
                                 const float* __restrict__ b_s,
                                 const float* __restrict__ W_t,
                                 const float* __restrict__ b_t,
                                 float* __restrict__ out_fs,
                                 float* __restrict__ out_ft,
                                 float* __restrict__ fsw,
                                 float* __restrict__ ftw)
{
    const int row = blockIdx.x;
    const int z   = blockIdx.y;
    const float* f    = z == 0 ? f_s : f_t;
    const float* W    = z == 0 ? W_s : W_t;
    const float* bias = z == 0 ? b_s : b_t;
    float* out        = z == 0 ? out_fs : out_ft;
    float* fw         = z == 0 ? fsw : ftw;

    __shared__ __align__(16) float frow[SDIM];
    const int t  = threadIdx.x;        // 0..255
    const int d  = t & 127;
    const int kh = t >> 7;             // 0/1
    for (int k = t; k < SDIM; k += 256) frow[k] = f[row * SDIM + k];
    __syncthreads();

    float acc = 0.0f;
    const int k0 = kh * (SDIM / 2);
    for (int k = k0; k < k0 + SDIM / 2; ++k)
        acc = fmaf(frow[k], W[k * FEAT + d], acc);

    __shared__ float part[2][128];
    part[kh][d] = acc;
    __syncthreads();

    const float a = part[0][d] + part[1][d] + bias[d];

    __shared__ float red[256];
    red[t] = (t < 128) ? a * a : 0.0f;
    __syncthreads();
    for (int s = 128; s > 0; s >>= 1) {
        if (t < s) red[t] += red[t + s];
        __syncthreads();
    }
    if (t < 128) {
        const float v = a * (1.0f / sqrtf(red[0]));
        out[row * FEAT + t] = v;
        fw[row * FEAT + t]  = v;
    }
}

// ---- K2a: DT[b][row] = dot(mem[row], fW[b])  (tall-skinny fp32 GEMM) ----
// 256 thr; block tile 256 rows x 64 b; thread tile 8 rows (stride 32) x 8 b.
// A in slot-major LDS with padded planes (conflict-free reads, coalesced
// global staging); F full-K in LDS (broadcast reads).
__global__ __launch_bounds__(256, 2)
void dgemm_kernel(const float* __restrict__ fW,   // [64][128], 16B-aligned
                  const float* __restrict__ mem,  // [NDATA][128]
                  float* __restrict__ DT)         // [64][NDATA]
{
    const int rbase = blockIdx.x * GR;
    const int t  = threadIdx.x;
    const int rg = t & 31;
    const int bg = t >> 5;             // 0..7

    __shared__ __align__(16) float4 At4[8 * APAD];   // ~32.9 KB
    __shared__ __align__(16) float4 Fl4[64 * 32];    // 32 KB

    // stage F (coalesced float4)
    {
        const float4* src = (const float4*)fW;
        #pragma unroll
        for (int c = 0; c < 8; ++c) Fl4[t + 256 * c] = src[t + 256 * c];
    }

    float acc[8][8];
    #pragma unroll
    for (int i = 0; i < 8; ++i)
        #pragma unroll
        for (int j = 0; j < 8; ++j) acc[i][j] = 0.0f;

    const int sslot = t & 7;           // staging slot (k-quad within chunk)
    const int srow0 = t >> 3;          // 0..31: row within each 32-row group

    for (int kc = 0; kc < 4; ++kc) {   // k-chunk: cols [kc*32, kc*32+32)
        __syncthreads();               // protect At4 readers of prev chunk
        // stage A: instr j covers rows j*32+srow0; 8 consecutive lanes read
        // one row's 128B chunk -> 8 lines per instruction (coalesced)
        #pragma unroll
        for (int j = 0; j < 8; ++j) {
            const int r  = j * 32 + srow0;
            const int gr = rbase + r;
            const int grc = gr < NDATA ? gr : NDATA - 1;
            At4[sslot * APAD + r] =
                *(const float4*)(mem + (size_t)grc * FEAT + kc * 32 + sslot * 4);
        }
        __syncthreads();

        #pragma unroll
        for (int s4 = 0; s4 < 8; ++s4) {
            const float4* ap = &At4[s4 * APAD + rg];
            const float4 a0 = ap[0];
            const float4 a1 = ap[32];
            const float4 a2 = ap[64];
            const float4 a3 = ap[96];
            const float4 a4 = ap[128];
            const float4 a5 = ap[160];
            const float4 a6 = ap[192];
            const float4 a7 = ap[224];
            const int kq = kc * 8 + s4;
            #pragma unroll
            for (int j = 0; j < 8; ++j) {
                const float4 fv = Fl4[(bg * 8 + j) * 32 + kq];
                FMA4(acc[0][j], a0, fv);
                FMA4(acc[1][j], a1, fv);
                FMA4(acc[2][j], a2, fv);
                FMA4(acc[3][j], a3, fv);
                FMA4(acc[4][j], a4, fv);
                FMA4(acc[5][j], a5, fv);
                FMA4(acc[6][j], a6, fv);
                FMA4(acc[7][j], a7, fv);
            }
        }
    }

    // DT store: lanes rg consecutive -> contiguous 4B -> coalesced
    #pragma unroll
    for (int j = 0; j < 8; ++j) {
        const int b = bg * 8 + j;
        float* drow = DT + (size_t)b * NDATA + rbase + rg;
        #pragma unroll
        for (int i = 0; i < 8; ++i) {
            if (rbase + rg + i * 32 < NDATA) drow[i * 32] = acc[i][j];
        }
    }
}

// ---- K2b: out_raw[b][k] = exp(DT[b][ci[b,k]] / T), accumulate Ssum ----
__global__ void gather_kernel(const int* __restrict__ contrast_idx,
                              const float* __restrict__ DT,
                              float* __restrict__ out_raw_z,  // [B*PK]
                              float* __restrict__ Ssum_z)     // scalar
{
    const int b   = blockIdx.y;
    const int ks  = blockIdx.x;
    const int tid = threadIdx.x;
    const int k0  = ks * KSEG;
    const int kend = min(k0 + KSEG, PK);
    const float inv_t = 1.0f / 0.07f;
    const float* dtb = DT + (size_t)b * NDATA;
    float lsum = 0.0f;
    #pragma unroll 4
    for (int k = k0 + tid; k < kend; k += 256) {
        const int ci = contrast_idx[(size_t)b * PK + k];
        const float v = expf(dtb[ci] * inv_t);
        out_raw_z[(size_t)b * PK + k] = v;
        lsum += v;
    }
    __shared__ float red[256];
    red[tid] = lsum;
    __syncthreads();
    for (int s = 128; s > 0; s >>= 1) {
        if (tid < s) red[tid] += red[tid + s];
        __syncthreads();
    }
    if (tid == 0) atomicAdd(Ssum_z, red[0]);
}

// ---- FALLBACK dots (R7): used only if ws too small for the D-table ----
__global__ __launch_bounds__(64)
void dots_kernel(const float* __restrict__ fsn,
                 const float* __restrict__ ftn,
                 const int*   __restrict__ contrast_idx,
                 const float* __restrict__ mem_s,
                 const float* __restrict__ mem_t,
                 float* __restrict__ out_raw,
                 float* __restrict__ Ssum)
{
    const int z = blockIdx.z;
    const int b = blockIdx.y;
    const int l = threadIdx.x;
    const int kchunk = blockIdx.x * WCHUNK;

    const float* f   = (z == 0 ? fsn : ftn) + b * FEAT;
    const float* mem = (z == 0 ? mem_t : mem_s);

    __shared__ __align__(16) float rows[2][TILE * FEAT];
    __shared__ __align__(16) float fl[FEAT];
    __shared__ int cis[WCHUNK];

    fl[l]      = f[l];
    fl[l + 64] = f[l + 64];
    for (int i = l; i < WCHUNK; i += 64) {
        const int k = kchunk + i;
        cis[i] = contrast_idx[(size_t)b * PK + (k < PK ? k : PK - 1)];
    }
    __syncthreads();

    const int q   = l >> 4;
    const int r_c = l & 15;
    const int xk  = r_c & 7;
    const int rh  = l >> 5;
    const int sl  = l & 31;

    const float4* fg = (const float4*)fl;
    const float4 f0 = fg[q * 8 + 0], f1 = fg[q * 8 + 1];
    const float4 f2 = fg[q * 8 + 2], f3 = fg[q * 8 + 3];
    const float4 f4 = fg[q * 8 + 4], f5 = fg[q * 8 + 5];
    const float4 f6 = fg[q * 8 + 6], f7 = fg[q * 8 + 7];

    const float inv_t = 1.0f / 0.07f;
    const size_t obase = (size_t)z * (B * PK) + (size_t)b * PK;
    float lsum = 0.0f;

#define STAGE(tt, bf) do { \
    _Pragma("unroll") \
    for (int p_ = 0; p_ < 8; ++p_) { \
        const int rr_ = 2 * p_ + rh; \
        const int ci_ = cis[(tt) * TILE + rr_]; \
        const float* g_ = mem + (size_t)ci_ * FEAT + ((sl ^ (rr_ & 7)) << 2); \
        GLL16(g_, &rows[bf][p_ * 256]); \
    } } while (0)

    STAGE(0, 0);
    int cur = 0;
    for (int t = 0; t < NT; ++t) {
        if (t + 1 < NT) {
            STAGE(t + 1, cur ^ 1);
            asm volatile("s_waitcnt vmcnt(8)" ::: "memory");
        } else {
            asm volatile("s_waitcnt vmcnt(0)" ::: "memory");
        }
        __builtin_amdgcn_sched_barrier(0);

        const float* rbase = &rows[cur][r_c * FEAT];
        float dot;
        {
            const float4 m0 = *(const float4*)(rbase + (((q * 8 + 0) ^ xk) << 2));
            const float4 m1 = *(const float4*)(rbase + (((q * 8 + 1) ^ xk) << 2));
            const float4 m2 = *(const float4*)(rbase + (((q * 8 + 2) ^ xk) << 2));
            const float4 m3 = *(const float4*)(rbase + (((q * 8 + 3) ^ xk) << 2));
            const float4 m4 = *(const float4*)(rbase + (((q * 8 + 4) ^ xk) << 2));
            const float4 m5 = *(const float4*)(rbase + (((q * 8 + 5) ^ xk) << 2));
            const float4 m6 = *(const float4*)(rbase + (((q * 8 + 6) ^ xk) << 2));
            const float4 m7 = *(const float4*)(rbase + (((q * 8 + 7) ^ xk) << 2));
            dot = m0.x * f0.x;
            dot = fmaf(m0.y, f0.y, dot); dot = fmaf(m0.z, f0.z, dot); dot = fmaf(m0.w, f0.w, dot);
            dot = fmaf(m1.x, f1.x, dot); dot = fmaf(m1.y, f1.y, dot); dot = fmaf(m1.z, f1.z, dot); dot = fmaf(m1.w, f1.w, dot);
            dot = fmaf(m2.x, f2.x, dot); dot = fmaf(m2.y, f2.y, dot); dot = fmaf(m2.z, f2.z, dot); dot = fmaf(m2.w, f2.w, dot);
            dot = fmaf(m3.x, f3.x, dot); dot = fmaf(m3.y, f3.y, dot); dot = fmaf(m3.z, f3.z, dot); dot = fmaf(m3.w, f3.w, dot);
            dot = fmaf(m4.x, f4.x, dot); dot = fmaf(m4.y, f4.y, dot); dot = fmaf(m4.z, f4.z, dot); dot = fmaf(m4.w, f4.w, dot);
            dot = fmaf(m5.x, f5.x, dot); dot = fmaf(m5.y, f5.y, dot); dot = fmaf(m5.z, f5.z, dot); dot = fmaf(m5.w, f5.w, dot);
            dot = fmaf(m6.x, f6.x, dot); dot = fmaf(m6.y, f6.y, dot); dot = fmaf(m6.z, f6.z, dot); dot = fmaf(m6.w, f6.w, dot);
            dot = fmaf(m7.x, f7.x, dot); dot = fmaf(m7.y, f7.y, dot); dot = fmaf(m7.z, f7.z, dot); dot = fmaf(m7.w, f7.w, dot);
        }
        dot += __shfl_xor(dot, 16);
        dot += __shfl_xor(dot, 32);

        const int krow = kchunk + t * TILE + r_c;
        if (q == 0 && krow < PK) {
            const float val = expf(dot * inv_t);
            out_raw[obase + krow] = val;
            lsum += val;
        }
        cur ^= 1;
    }
#undef STAGE

    lsum += __shfl_xor(lsum, 8);
    lsum += __shfl_xor(lsum, 4);
    lsum += __shfl_xor(lsum, 2);
    lsum += __shfl_xor(lsum, 1);
    if (l == 0) atomicAdd(&Ssum[z], lsum);
}

// ---- K3: accumulate acc[z] = sum logD1 + P * sum logD0 (weighted) ----
__global__ void ccd_loss_kernel(const float* __restrict__ out_raw,
                                const float* __restrict__ Ssum,
                                float* __restrict__ acc)
{
    const int z = blockIdx.y;
    const float S = Ssum[z];
    const float c = ((float)(B * PK)) / (S * (float)NDATA);

    const int total = B * PK;
    float contrib = 0.0f;
    for (int i = blockIdx.x * blockDim.x + threadIdx.x; i < total;
         i += gridDim.x * blockDim.x) {
        const float v = out_raw[(size_t)z * total + i] * c;
        const int k = i % PK;
        if (k < P) {
            contrib += logf(v / (v + M_PN + EPSC));
        } else {
            contrib += (float)P * logf(M_PN / (v + M_PN + EPSC));
        }
    }
    __shared__ float red[256];
    red[threadIdx.x] = contrib;
    __syncthreads();
    for (int s = 128; s > 0; s >>= 1) {
        if (threadIdx.x < s) red[threadIdx.x] += red[threadIdx.x + s];
        __syncthreads();
    }
    if (threadIdx.x == 0) atomicAdd(&acc[z], red[0]);
}

// ---- K4: upd[z][b] = l2norm(mem[idx[b]]*0.5 + f[b]*0.5) ----
__global__ void upd_kernel(const float* __restrict__ fsn,
                           const float* __restrict__ ftn,
                           const int*   __restrict__ idx,
                           const float* __restrict__ mem_s,
                           const float* __restrict__ mem_t,
                           float* __restrict__ upd)
{
    const int z = blockIdx.y;
    const int b = blockIdx.x;
    const int d = threadIdx.x;
    const float* mem = z == 0 ? mem_s : mem_t;
    const float* f   = z == 0 ? fsn : ftn;
    const int i = idx[b];
    const float v = mem[(size_t)i * FEAT + d] * 0.5f + f[b * FEAT + d] * 0.5f;
    __shared__ float red[128];
    red[d] = v * v;
    __syncthreads();
    for (int s = 64; s > 0; s >>= 1) {
        if (d < s) red[d] += red[d + s];
        __syncthreads();
    }
    upd[(size_t)z * (B * FEAT) + b * FEAT + d] = v * (1.0f / sqrtf(red[0]));
}

// ---- K4b: remap[e] = last b with idx[b]==class_index[e], else -1 ----
__global__ void remap_kernel(const int* __restrict__ class_index,
                             const int* __restrict__ idx,
                             int* __restrict__ remap)
{
    const int e = blockIdx.x * 256 + threadIdx.x;
    if (e >= NCLS * PER) return;
    const int ci = class_index[e];
    int rb = -1;
    for (int b = B - 1; b >= 0; --b) {
        if (idx[b] == ci) { rb = b; break; }
    }
    remap[e] = rb;
}

// ---- K5a ----
__global__ void anchors_partial_kernel(const int* __restrict__ class_index,
                                       const int* __restrict__ remap,
                                       const float* __restrict__ mem_s,
                                       const float* __restrict__ mem_t,
                                       const float* __restrict__ upd,
                                       float* __restrict__ partial)
{
    const int z     = blockIdx.z;
    const int c     = blockIdx.y;
    const int chunk = blockIdx.x;
    const int d     = threadIdx.x;
    const float* mem = z == 0 ? mem_s : mem_t;
    const float* u   = upd + (size_t)z * (B * FEAT);
    float acc = 0.0f;
    #pragma unroll 4
    for (int j = chunk * CS; j < chunk * CS + CS; ++j) {
        const int e = c * PER + j;
        const int ci = class_index[e];
        const int rb = remap[e];
        const float* row = (rb >= 0) ? (u + rb * FEAT) : (mem + (size_t)ci * FEAT);
        const float v = row[d];
        acc += v > 0.0f ? v : 0.0f;
    }
    atomicAdd(&partial[(size_t)z * (NCLS * FEAT) + c * FEAT + d], acc);
}

// ---- K5b ----
__global__ void anchors_finish_kernel(const float* __restrict__ partial,
                                      float* __restrict__ anchors)
{
    const int z = blockIdx.y;
    const int c = blockIdx.x;
    const int d = threadIdx.x;
    const float meanv = partial[(size_t)z * (NCLS * FEAT) + c * FEAT + d]
                        * (1.0f / (float)PER);
    __shared__ float red[128];
    red[d] = meanv * meanv;
    __syncthreads();
    for (int s = 64; s > 0; s >>= 1) {
        if (d < s) red[d] += red[d + s];
        __syncthreads();
    }
    anchors[(size_t)z * (NCLS * FEAT) + c * FEAT + d] = meanv * (1.0f / sqrtf(red[0]));
}

// ---- K6 ----
__global__ void final_kernel(const float* __restrict__ fsn,
                             const float* __restrict__ ftn,
                             const float* __restrict__ anchors,
                             const float* __restrict__ acc,
                             float* __restrict__ d_out)
{
    __shared__ float sa[NCLS * FEAT];
    __shared__ float ta[NCLS * FEAT];
    const int tid = threadIdx.x;
    for (int i = tid; i < NCLS * FEAT; i += 64) {
        sa[i] = anchors[i];
        ta[i] = anchors[NCLS * FEAT + i];
    }
    __syncthreads();

    const int b = tid;
    float srel[NCLS], trel[NCLS];
    for (int j = 0; j < NCLS; ++j) { srel[j] = 0.0f; trel[j] = 0.0f; }
    for (int d = 0; d < FEAT; ++d) {
        const float fs = fsn[b * FEAT + d];
        const float ft = ftn[b * FEAT + d];
        #pragma unroll
        for (int j = 0; j < NCLS; ++j) {
            srel[j] = fmaf(fs, sa[j * FEAT + d], srel[j]);
            trel[j] = fmaf(ft, ta[j * FEAT + d], trel[j]);
        }
    }
    const float inv_t = 1.0f / 0.07f;
    float smax = -1e30f, tmax = -1e30f;
    for (int j = 0; j < NCLS; ++j) {
        srel[j] *= inv_t; trel[j] *= inv_t;
        smax = fmaxf(smax, srel[j]);
        tmax = fmaxf(tmax, trel[j]);
    }
    float ssum = 0.0f, tsum = 0.0f;
    float texp[NCLS];
    for (int j = 0; j < NCLS; ++j) {
        ssum += expf(srel[j] - smax);
        texp[j] = expf(trel[j] - tmax);
        tsum += texp[j];
    }
    const float lse_s = logf(ssum);
    float contrib = 0.0f;
    for (int j = 0; j < NCLS; ++j) {
        const float tgt = texp[j] / tsum;
        const float log_in = srel[j] - smax - lse_s;
        contrib += tgt * (logf(tgt + 1e-30f) - log_in);
    }
    for (int off = 32; off > 0; off >>= 1) contrib += __shfl_down(contrib, off);
    if (tid == 0) {
        d_out[1] = contrib / (float)B;
        d_out[0] = -(acc[0] + acc[1]) / (float)(B * P);
    }
}

extern "C" void kernel_launch(void* const* d_in, const int* in_sizes, int n_in,
                              void* d_out_v, int out_size, void* d_ws, size_t ws_size,
                              hipStream_t stream)
{
    const float* f_s = (const float*)d_in[0];
    const float* f_t = (const float*)d_in[1];
    const int*   idx = (const int*)d_in[2];
    const int*   class_index = (const int*)d_in[4];
    const int*   contrast_idx = (const int*)d_in[6];
    const float* W_s = (const float*)d_in[7];
    const float* b_s = (const float*)d_in[8];
    const float* W_t = (const float*)d_in[9];
    const float* b_t = (const float*)d_in[10];
    const float* mem_s = (const float*)d_in[11];
    const float* mem_t = (const float*)d_in[12];

    float* out    = (float*)d_out_v;
    float* out_fs = out + 2;
    float* out_ft = out + 2 + B * FEAT;

    float* ws = (float*)d_ws;
    const size_t fl = ws_size / sizeof(float);
    const size_t REST = 2 * (size_t)B * PK
                      + 2 * 64 * FEAT
                      + 2 * B * FEAT
                      + 4 * NCLS * FEAT
                      + NCLS * PER
                      + 64;
    const bool big   = fl >= 2 * (size_t)DTSZ + REST;
    const bool small = fl >= 1 * (size_t)DTSZ + REST;

    if (small) {
        // ---------- D-table path ----------
        float* DT0 = ws;
        float* DT1 = big ? ws + DTSZ : DT0;
        float* out_raw = (big ? ws + 2 * (size_t)DTSZ : ws + DTSZ);
        float* fsw     = out_raw + 2 * (size_t)B * PK;   // 16B-aligned
        float* ftw     = fsw + 64 * FEAT;
        float* upd     = ftw + 64 * FEAT;
        float* anchors = upd + 2 * B * FEAT;
        float* partial = anchors + 2 * NCLS * FEAT;
        float* Ssum    = partial + 2 * NCLS * FEAT;      // [2]
        float* acc     = Ssum + 2;                       // [2]
        int*   remap   = (int*)(acc + 2);

        hipMemsetAsync(Ssum, 0, 4 * sizeof(float), stream);
        hipMemsetAsync(partial, 0, 2 * NCLS * FEAT * sizeof(float), stream);

        dim3 g1(B, 2);
        gemm_norm_kernel<<<g1, 256, 0, stream>>>(f_s, f_t, W_s, b_s, W_t, b_t,
                                                 out_fs, out_ft, fsw, ftw);

        const int gblocks = (NDATA + GR - 1) / GR;   // 391
        dim3 gg(KSPLIT, B);
        if (big) {
            dgemm_kernel<<<gblocks, 256, 0, stream>>>(fsw, mem_t, DT0);
            dgemm_kernel<<<gblocks, 256, 0, stream>>>(ftw, mem_s, DT1);
            gather_kernel<<<gg, 256, 0, stream>>>(contrast_idx, DT0, out_raw, Ssum);
            gather_kernel<<<gg, 256, 0, stream>>>(contrast_idx, DT1,
                                                  out_raw + (size_t)B * PK, Ssum + 1);
        } else {
            dgemm_kernel<<<gblocks, 256, 0, stream>>>(fsw, mem_t, DT0);
            gather_kernel<<<gg, 256, 0, stream>>>(contrast_idx, DT0, out_raw, Ssum);
            dgemm_kernel<<<gblocks, 256, 0, stream>>>(ftw, mem_s, DT0);
            gather_kernel<<<gg, 256, 0, stream>>>(contrast_idx, DT0,
                                                  out_raw + (size_t)B * PK, Ssum + 1);
        }

        dim3 g3(256, 2);
        ccd_loss_kernel<<<g3, 256, 0, stream>>>(out_raw, Ssum, acc);
        dim3 g4(B, 2);
        upd_kernel<<<g4, 128, 0, stream>>>(out_fs, out_ft, idx, mem_s, mem_t, upd);
        remap_kernel<<<(NCLS * PER + 255) / 256, 256, 0, stream>>>(class_index, idx, remap);
        dim3 g5a(JCHUNKS, NCLS, 2);
        anchors_partial_kernel<<<g5a, 128, 0, stream>>>(class_index, remap,
                                                        mem_s, mem_t, upd, partial);
        dim3 g5b(NCLS, 2);
        anchors_finish_kernel<<<g5b, 128, 0, stream>>>(partial, anchors);
        final_kernel<<<1, 64, 0, stream>>>(out_fs, out_ft, anchors, acc, out);
    } else {
        // ---------- fallback: R7 layout & path ----------
        float* out_raw = ws;
        float* Ssum    = out_raw + 2 * (B * PK);
        float* acc     = Ssum + 2;
        float* upd     = acc + 2;
        float* anchors = upd + 2 * (B * FEAT);
        float* partial = anchors + 2 * (NCLS * FEAT);
        int*   remap   = (int*)(partial + 2 * (NCLS * FEAT));

        hipMemsetAsync(Ssum, 0, 4 * sizeof(float), stream);
        hipMemsetAsync(partial, 0, 2 * NCLS * FEAT * sizeof(float), stream);

        dim3 g1(B, 2);
        gemm_norm_kernel<<<g1, 256, 0, stream>>>(f_s, f_t, W_s, b_s, W_t, b_t,
                                                 out_fs, out_ft,
                                                 out_fs, out_ft);
        dim3 g2((PK + WCHUNK - 1) / WCHUNK, B, 2);
        dots_kernel<<<g2, 64, 0, stream>>>(out_fs, out_ft, contrast_idx,
                                           mem_s, mem_t, out_raw, Ssum);
        dim3 g3(256, 2);
        ccd_loss_kernel<<<g3, 256, 0, stream>>>(out_raw, Ssum, acc);
        dim3 g4(B, 2);
        upd_kernel<<<g4, 128, 0, stream>>>(out_fs, out_ft, idx, mem_s, mem_t, upd);
        remap_kernel<<<(NCLS * PER + 255) / 256, 256, 0, stream>>>(class_index, idx, remap);
        dim3 g5a(JCHUNKS, NCLS, 2);
        anchors_partial_kernel<<<g5a, 128, 0, stream>>>(class_index, remap,
                                                        mem_s, mem_t, upd, partial);
        dim3 g5b(NCLS, 2);
        anchors_finish_kernel<<<g5b, 128, 0, stream>>>(partial, anchors);
        final_kernel<<<1, 64, 0, stream>>>(out_fs, out_ft, anchors, acc, out);
    }
}